// Round 20
// baseline (471.449 us; speedup 1.0000x reference)
//
#include <hip/hip_runtime.h>
#include <hip/hip_bf16.h>
#include <math.h>

#define T_TOK 4096
#define D_DIM 1024
#define E_EXP 8
#define FF_DIM 4096
#define NROWS (T_TOK * 2)
#define MAXT1 40   // max m-tiles (BM=256): 8192/256 + 8
#define MAXT2 72   // max m-tiles (BM=128): 8192/128 + 8
#define NBLK1 (32 * MAXT1)      // pass1 grid size (n-tiles x MAXT1)
#define W2TILES (E_EXP * (FF_DIM / 64) * (D_DIM / 64))   // 8192

typedef unsigned short u16;
typedef unsigned int u32;
typedef __attribute__((ext_vector_type(8))) short bf16x8;
typedef __attribute__((ext_vector_type(4))) float f32x4;
typedef __attribute__((ext_vector_type(2))) unsigned int u32x2;
typedef __attribute__((ext_vector_type(4))) short s16x4;

__device__ __forceinline__ u16 f2bf(float f) {
    union { float f; unsigned u; } v; v.f = f;
    unsigned r = v.u + 0x7FFFu + ((v.u >> 16) & 1u);
    return (u16)(r >> 16);
}

typedef const __attribute__((address_space(1))) u32* gas1_t;
typedef __attribute__((address_space(3))) u32* las3_t;
#define GLOAD16(g, l) __builtin_amdgcn_global_load_lds((gas1_t)(const void*)(g), (las3_t)(void*)(l), 16, 0, 0)
#define MFMA(a, b, c) __builtin_amdgcn_mfma_f32_16x16x32_bf16((a), (b), (c), 0, 0, 0)
#define CVTPK(dst, lo, hi) asm("v_cvt_pk_bf16_f32 %0, %1, %2" : "=v"(dst) : "v"(lo), "v"(hi))
#define CFENCE() asm volatile("" ::: "memory")
// B-tile swizzle for fused pass1: sigma(row) = (row ^ (row>>2)) & 7.
#define SIGB(r) (((r) ^ ((r) >> 2)) & 7)

// ---------------- small kernels ----------------

__global__ void k_init(int* cnt, float* probsum) {
    int i = threadIdx.x;
    if (i < E_EXP) { cnt[i] = 0; probsum[i] = 0.f; }
}

__global__ __launch_bounds__(256) void k_router(
    const float* __restrict__ x, const float* __restrict__ Wr,
    int* __restrict__ tok_e, float* __restrict__ tok_w,
    int* __restrict__ cnt, float* __restrict__ probsum)
{
    __shared__ float bp[E_EXP];
    __shared__ int   bc[E_EXP];
    const int tid = threadIdx.x;
    if (tid < E_EXP) { bp[tid] = 0.f; bc[tid] = 0; }
    __syncthreads();
    const int wave = tid >> 6, lane = tid & 63;
    const int t = blockIdx.x * 4 + wave;
    const float* xt = x + (size_t)t * D_DIM;
    float a[E_EXP] = {0.f,0.f,0.f,0.f,0.f,0.f,0.f,0.f};
    for (int j = lane; j < D_DIM; j += 64) {
        float xv = xt[j];
        #pragma unroll
        for (int e = 0; e < E_EXP; e++) a[e] = fmaf(xv, Wr[e * D_DIM + j], a[e]);
    }
    #pragma unroll
    for (int e = 0; e < E_EXP; e++) {
        #pragma unroll
        for (int off = 32; off; off >>= 1) a[e] += __shfl_xor(a[e], off, 64);
    }
    if (lane == 0) {
        float mx = a[0];
        #pragma unroll
        for (int e = 1; e < E_EXP; e++) mx = fmaxf(mx, a[e]);
        float p[E_EXP], s = 0.f;
        #pragma unroll
        for (int e = 0; e < E_EXP; e++) { p[e] = expf(a[e] - mx); s += p[e]; }
        float inv = 1.f / s;
        #pragma unroll
        for (int e = 0; e < E_EXP; e++) { p[e] *= inv; atomicAdd(&bp[e], p[e]); }
        int e0 = 0; float v0 = p[0];
        #pragma unroll
        for (int e = 1; e < E_EXP; e++) if (p[e] > v0) { v0 = p[e]; e0 = e; }
        int e1 = -1; float v1 = -1.f;
        #pragma unroll
        for (int e = 0; e < E_EXP; e++) if (e != e0 && p[e] > v1) { v1 = p[e]; e1 = e; }
        float sv = v0 + v1 + 1e-6f;
        tok_e[2*t] = e0; tok_e[2*t+1] = e1;
        tok_w[2*t] = v0 / sv; tok_w[2*t+1] = v1 / sv;
        atomicAdd(&bc[e0], 1); atomicAdd(&bc[e1], 1);
    }
    __syncthreads();
    if (tid < E_EXP) { atomicAdd(&cnt[tid], bc[tid]); atomicAdd(&probsum[tid], bp[tid]); }
}

__global__ void k_prefix(const int* __restrict__ cnt, const float* __restrict__ probsum,
                         int* __restrict__ basep, int* __restrict__ cursor,
                         float* __restrict__ out_lb,
                         int* __restrict__ nt1, int* __restrict__ te1, int* __restrict__ tm1,
                         int* __restrict__ nt2, int* __restrict__ te2, int* __restrict__ tm2)
{
    if (threadIdx.x == 0) {
        int b = 0; float lb = 0.f;
        for (int e = 0; e < E_EXP; e++) {
            basep[e] = b; b += cnt[e];
            lb += ((float)cnt[e] / (8192.f + 1e-6f)) * probsum[e];
        }
        *out_lb = lb * (float)E_EXP;
        int n1 = 0, n2 = 0;
        for (int e = 0; e < E_EXP; e++) {
            for (int m = 0; m < cnt[e]; m += 256) { te1[n1] = e; tm1[n1] = m; n1++; }
            for (int m = 0; m < cnt[e]; m += 128) { te2[n2] = e; tm2[n2] = m; n2++; }
        }
        *nt1 = n1; *nt2 = n2;
    }
    if (threadIdx.x < E_EXP) cursor[threadIdx.x] = 0;
}

__global__ void k_assign(const int* __restrict__ tok_e, const float* __restrict__ tok_w,
                         const int* __restrict__ basep, int* __restrict__ cursor,
                         int* __restrict__ row_token, int* __restrict__ row_slot,
                         float* __restrict__ row_weight)
{
    int t = blockIdx.x * blockDim.x + threadIdx.x;
    if (t >= T_TOK) return;
    #pragma unroll
    for (int k = 0; k < 2; k++) {
        int e = tok_e[2*t + k];
        int pos = basep[e] + atomicAdd(&cursor[e], 1);
        row_token[pos] = t; row_slot[pos] = k; row_weight[pos] = tok_w[2*t + k];
    }
}

__global__ __launch_bounds__(256) void k_cvt_x(const float* __restrict__ in, u16* __restrict__ out) {
    size_t i = ((size_t)blockIdx.x * 256 + threadIdx.x) * 8;
    f32x4 a = *(const f32x4*)(in + i);
    f32x4 b = *(const f32x4*)(in + i + 4);
    bf16x8 o;
    #pragma unroll
    for (int j = 0; j < 4; j++) { o[j] = (short)f2bf(a[j]); o[j + 4] = (short)f2bf(b[j]); }
    *(bf16x8*)(out + i) = o;
}

// ---------------- pass 1: hg = silu(x@Wg) * (x@W1)  [+ W2 cvt epilogue] ----------------
// GEMM part unchanged from R17/R19 (fused fp32 W1/Wg transpose-convert, SIGB
// swizzle, one drain+barrier per K-tile). NEW: every block (dead ones
// immediately, live ones after the GEMM epilogue) transposes ~6.4 of W2's 8192
// 64x64 tiles into w2t (bf16 [E][D][FF]), reusing this kernel's LDS — this
// replaces the serial 43us k_cvt_w2 prepass; pass2 (reader) launches after.

__global__ __launch_bounds__(512, 2) void k_pass1(
    const u16* __restrict__ xbf,
    const float* __restrict__ W1, const float* __restrict__ Wg,
    const float* __restrict__ b1v, const float* __restrict__ bgv,
    const float* __restrict__ W2, u16* __restrict__ w2t,
    const int* __restrict__ cnt, const int* __restrict__ basep,
    const int* __restrict__ row_token,
    const int* __restrict__ ntp, const int* __restrict__ te, const int* __restrict__ tm,
    u16* __restrict__ hg)
{
    __shared__ __align__(16) u16 LDS[2 * 32768];
    const int tid = threadIdx.x;
    const int ty = blockIdx.y;

    if (ty < *ntp) {
        const int e = te[ty];
        const int m0 = tm[ty];
        const int count = cnt[e];
        const int rbase = basep[e];
        const int n0 = blockIdx.x * 128;

        const int l = tid & 63;
        const int w = tid >> 6;

        const int rb = tid >> 3;
        const int swA = ((tid & 7) ^ ((tid >> 3) & 7)) * 8;
        const u16* sA[4];
        #pragma unroll
        for (int s = 0; s < 4; s++) {
            int g = m0 + rb + s * 64; if (g > count - 1) g = count - 1;
            sA[s] = xbf + (size_t)row_token[rbase + g] * D_DIM + swA;
        }

        const int nq = tid & 31;
        const int kq = tid >> 5;
        const float* pBh = W1 + ((size_t)e * D_DIM + kq * 4) * FF_DIM + n0 + nq * 4;
        const float* pBg = Wg + ((size_t)e * D_DIM + kq * 4) * FF_DIM + n0 + nq * 4;
        const int cW = kq >> 1;
        const int offW = (kq & 1) * 4;
        int wdst[4];
        #pragma unroll
        for (int j = 0; j < 4; j++) {
            const int row = nq * 4 + j;
            wdst[j] = row * 64 + (cW ^ SIGB(row)) * 8 + offW;
        }

        const int wm = w >> 2, wn = w & 3;
        const int fr = l & 15, q = l >> 4;
        const int s7 = fr & 7;

        f32x4 acc_h[8][2], acc_g[8][2];
        const f32x4 z4 = {0.f, 0.f, 0.f, 0.f};
        #pragma unroll
        for (int mf = 0; mf < 8; mf++)
            #pragma unroll
            for (int nf = 0; nf < 2; nf++) { acc_h[mf][nf] = z4; acc_g[mf][nf] = z4; }

        f32x4 vb0, vb1, vb2, vb3;

        #define LOADB1(P, K0) do { \
            const float* p_ = (P) + (size_t)(K0) * FF_DIM; \
            vb0 = *(const f32x4*)(p_); \
            vb1 = *(const f32x4*)(p_ + FF_DIM); \
            vb2 = *(const f32x4*)(p_ + 2 * FF_DIM); \
            vb3 = *(const f32x4*)(p_ + 3 * FF_DIM); \
        } while (0)

        #define CVTW1(BASE) do { \
            _Pragma("unroll") \
            for (int j = 0; j < 4; j++) { \
                u32 lo_, hi_; u32x2 wv_; \
                CVTPK(lo_, vb0[j], vb1[j]); \
                CVTPK(hi_, vb2[j], vb3[j]); \
                wv_.x = lo_; wv_.y = hi_; \
                *(u32x2*)&LDS[(BASE) + wdst[j]] = wv_; \
            } \
        } while (0)

        #define STAGE_A1(B, K0) do { \
            _Pragma("unroll") \
            for (int s = 0; s < 4; s++) \
                GLOAD16(sA[s] + (K0), &LDS[(B) * 32768 + s * 4096 + tid * 8]); \
        } while (0)

        auto COMP = [&](int kk, int ab) {
            const int rsA = ((kk * 4 + q) ^ s7) * 8;
            const int rB0 = wn * 32 + fr, rB1 = wn * 32 + 16 + fr;
            const int cb0 = ((kk * 4 + q) ^ SIGB(rB0)) * 8;
            const int cb1 = ((kk * 4 + q) ^ SIGB(rB1)) * 8;
            bf16x8 bh0 = *(const bf16x8*)&LDS[ab + 16384 + rB0 * 64 + cb0];
            bf16x8 bg0 = *(const bf16x8*)&LDS[ab + 24576 + rB0 * 64 + cb0];
            bf16x8 bh1 = *(const bf16x8*)&LDS[ab + 16384 + rB1 * 64 + cb1];
            bf16x8 bg1 = *(const bf16x8*)&LDS[ab + 24576 + rB1 * 64 + cb1];
            #define LDA1(i) (*(const bf16x8*)&LDS[ab + (wm * 128 + (i) * 16 + fr) * 64 + rsA])
            #define MF4(areg, i) do { \
                __builtin_amdgcn_s_setprio(1); \
                acc_h[i][0] = MFMA(areg, bh0, acc_h[i][0]); \
                acc_h[i][1] = MFMA(areg, bh1, acc_h[i][1]); \
                acc_g[i][0] = MFMA(areg, bg0, acc_g[i][0]); \
                acc_g[i][1] = MFMA(areg, bg1, acc_g[i][1]); \
                __builtin_amdgcn_s_setprio(0); } while (0)
            bf16x8 aA = LDA1(0);
            bf16x8 aB = LDA1(1);
            bf16x8 aC;
            aC = LDA1(2); MF4(aA, 0);
            aA = LDA1(3); MF4(aB, 1);
            aB = LDA1(4); MF4(aC, 2);
            aC = LDA1(5); MF4(aA, 3);
            aA = LDA1(6); MF4(aB, 4);
            aB = LDA1(7); MF4(aC, 5);
            MF4(aA, 6);
            MF4(aB, 7);
            #undef LDA1
            #undef MF4
        };

        const int NT = D_DIM / 64;   // 16
        LOADB1(pBh, 0);
        CVTW1(0 + 16384);
        STAGE_A1(0, 0);
        LOADB1(pBg, 0);
        CVTW1(0 + 24576);
        asm volatile("s_waitcnt vmcnt(0) lgkmcnt(0)" ::: "memory");
        __builtin_amdgcn_s_barrier();
        CFENCE();

        int b = 0;
        #pragma unroll 1
        for (int t = 0; t < NT; ++t) {
            const int ab = b * 32768;
            const int nboff = (b ^ 1) * 32768;
            const int kN = (t + 1 < NT ? t + 1 : NT - 1) * 64;
            LOADB1(pBh, kN);
            COMP(0, ab);
            CVTW1(nboff + 16384);
            STAGE_A1(b ^ 1, kN);
            LOADB1(pBg, kN);
            COMP(1, ab);
            CVTW1(nboff + 24576);
            asm volatile("s_waitcnt vmcnt(0) lgkmcnt(0)" ::: "memory");
            __builtin_amdgcn_s_barrier();
            CFENCE();
            b ^= 1;
        }
        asm volatile("s_waitcnt vmcnt(0)" ::: "memory");
        #undef LOADB1
        #undef CVTW1
        #undef STAGE_A1

        const float* b1p = b1v + (size_t)e * FF_DIM + n0;
        const float* bgp = bgv + (size_t)e * FF_DIM + n0;
        #pragma unroll
        for (int mf = 0; mf < 8; mf++) {
            const int rl = wm * 128 + mf * 16 + q * 4;
            #pragma unroll
            for (int r = 0; r < 4; r++) {
                const int g = m0 + rl + r;
                if (g < count) {
                    u16* orow = hg + (size_t)(rbase + g) * FF_DIM + n0;
                    #pragma unroll
                    for (int nf = 0; nf < 2; nf++) {
                        const int col = wn * 32 + nf * 16 + fr;
                        float hv = acc_h[mf][nf][r] + b1p[col];
                        float gv = acc_g[mf][nf][r] + bgp[col];
                        float sig = 1.f / (1.f + expf(-gv));
                        orow[col] = f2bf(gv * sig * hv);
                    }
                }
            }
        }
    }

    // ---- W2 cvt epilogue: transpose 64x64 fp32 tiles -> bf16 w2t ----
    // tile id -> (expert e2, FF-tile rt, D-tile ct); 1024 tiles per expert.
    {
        const int bid = ty * gridDim.x + blockIdx.x;   // 0..NBLK1-1
        const int lr = tid >> 4;                       // 0..31
        const int lc = (tid & 15) * 4;
        u16* tbuf = LDS;                               // [64][68] region
        #pragma unroll 1
        for (int tile = bid; tile < W2TILES; tile += NBLK1) {
            const int e2 = tile >> 10;
            const int rem = tile & 1023;
            const int r0 = (rem >> 4) * 64;            // FF offset
            const int c0 = (rem & 15) * 64;            // D offset
            const float* in = W2 + ((size_t)e2 * FF_DIM + r0) * D_DIM + c0;
            u16* outp = w2t + ((size_t)e2 * D_DIM + c0) * FF_DIM + r0;
            __syncthreads();
            #pragma unroll
            for (int h = 0; h < 2; h++) {
                const int r = lr + h * 32;
                f32x4 v = *(const f32x4*)(in + (size_t)r * D_DIM + lc);
                s16x4 wv;
                #pragma unroll
                for (int j = 0; j < 4; j++) wv[j] = (short)f2bf(v[j]);
                *(s16x4*)&tbuf[r * 68 + lc] = wv;
            }
            __syncthreads();
            #pragma unroll
            for (int h = 0; h < 2; h++) {
                const int c = lr + h * 32;
                s16x4 wv;
                #pragma unroll
                for (int j = 0; j < 4; j++) wv[j] = (short)tbuf[(lc + j) * 68 + c];
                *(s16x4*)(outp + (size_t)c * FF_DIM + lc) = wv;
            }
        }
    }
}

// ---------------- pass 2: contrib[slot] = w * (hg @ W2 + b2) ----------------
// R11/R17 config: BM=128 BN=128 BK=64, 4 waves (2Mx2N, 64x64/wave),
// 2x32KB dbuf -> 2 blocks/CU, depth-1 counted vmcnt(8), sigma(r)=r&7 swizzle,
// both operands bf16 via global_load_lds (w2t from pass1 epilogue).

__global__ __launch_bounds__(256, 2) void k_pass2(
    const u16* __restrict__ hg,
    const u16* __restrict__ w2t, const float* __restrict__ b2v,
    const int* __restrict__ cnt, const int* __restrict__ basep,
    const int* __restrict__ row_token, const int* __restrict__ row_slot,
    const float* __restrict__ row_weight,
    const int* __restrict__ ntp, const int* __restrict__ te, const int* __restrict__ tm,
    float* __restrict__ contrib)
{
    const int ty = blockIdx.y;
    if (ty >= *ntp) return;
    const int e = te[ty];
    const int m0 = tm[ty];
    const int count = cnt[e];
    const int rbase = basep[e];
    const int n0 = blockIdx.x * 128;

    __shared__ __align__(16) u16 LDS[2 * 16384];

    const int tid = threadIdx.x;
    const int l = tid & 63;
    const int w = tid >> 6;

    const int rb = tid >> 3;                        // 0..31
    const int sw0 = ((tid & 7) ^ ((tid >> 3) & 7)) * 8;
    const u16* sA[4];
    #pragma unroll
    for (int s = 0; s < 4; s++) {
        int g = m0 + rb + s * 32; if (g > count - 1) g = count - 1;
        sA[s] = hg + (size_t)(rbase + g) * FF_DIM + sw0;
    }
    const u16* sB[4];
    #pragma unroll
    for (int s = 0; s < 4; s++)
        sB[s] = w2t + ((size_t)e * D_DIM + (size_t)(n0 + rb + s * 32)) * FF_DIM + sw0;

    const int wm = w >> 1, wn = w & 1;   // 2M x 2N
    const int fr = l & 15, q = l >> 4;
    const int s7 = fr & 7;

    f32x4 acc[4][4];
    const f32x4 z4 = {0.f, 0.f, 0.f, 0.f};
    #pragma unroll
    for (int mf = 0; mf < 4; mf++)
        #pragma unroll
        for (int nf = 0; nf < 4; nf++) acc[mf][nf] = z4;

    auto STAGE = [&](int b, int k0) {
        #pragma unroll
        for (int s = 0; s < 4; s++)
            GLOAD16(sA[s] + k0, &LDS[b * 16384 + s * 2048 + tid * 8]);
        #pragma unroll
        for (int s = 0; s < 4; s++)
            GLOAD16(sB[s] + k0, &LDS[b * 16384 + 8192 + s * 2048 + tid * 8]);
    };

    const int NT = FF_DIM / 64;   // 64
    STAGE(0, 0);
    int cur = 0;
    #pragma unroll 1
    for (int t = 0; t < NT; ++t) {
        if (t + 1 < NT) {
            STAGE(cur ^ 1, (t + 1) * 64);
            asm volatile("s_waitcnt vmcnt(8)" ::: "memory");
        } else {
            asm volatile("s_waitcnt vmcnt(0)" ::: "memory");
        }
        __builtin_amdgcn_s_barrier();
        CFENCE();
        const int ab = cur * 16384;
        #pragma unroll
        for (int kk = 0; kk < 2; kk++) {
            const int rs = ((kk * 4 + q) ^ s7) * 8;
            bf16x8 a[4], bb[4];
            #pragma unroll
            for (int mf = 0; mf < 4; mf++)
                a[mf] = *(const bf16x8*)&LDS[ab + (wm * 64 + mf * 16 + fr) * 64 + rs];
            #pragma unroll
            for (int nf = 0; nf < 4; nf++)
                bb[nf] = *(const bf16x8*)&LDS[ab + 8192 + (wn * 64 + nf * 16 + fr) * 64 + rs];
            __builtin_amdgcn_s_setprio(1);
            #pragma unroll
            for (int mf = 0; mf < 4; mf++)
                #pragma unroll
                for (int nf = 0; nf < 4; nf++)
                    acc[mf][nf] = MFMA(a[mf], bb[nf], acc[mf][nf]);
            __builtin_amdgcn_s_setprio(0);
        }
        CFENCE();
        __builtin_amdgcn_s_barrier();
        cur ^= 1;
    }

    const float* b2p = b2v + (size_t)e * D_DIM + n0;
    #pragma unroll
    for (int mf = 0; mf < 4; mf++) {
        const int rl = wm * 64 + mf * 16 + q * 4;
        #pragma unroll
        for (int r = 0; r < 4; r++) {
            const int g = m0 + rl + r;
            if (g < count) {
                const int token = row_token[rbase + g];
                const int slot  = row_slot[rbase + g];
                const float wgt_ = row_weight[rbase + g];
                float* orow = contrib + ((size_t)slot * T_TOK + token) * D_DIM + n0;
                #pragma unroll
                for (int nf = 0; nf < 4; nf++) {
                    const int col = wn * 64 + nf * 16 + fr;
                    orow[col] = wgt_ * (acc[mf][nf][r] + b2p[col]);
                }
            }
        }
    }
}

__global__ void k_combine(const float* __restrict__ contrib, float* __restrict__ out) {
    int i = blockIdx.x * blockDim.x + threadIdx.x;
    const f32x4* c0 = (const f32x4*)contrib;
    const f32x4* c1 = c0 + ((size_t)T_TOK * D_DIM / 4);
    f32x4* o = (f32x4*)out;
    o[i] = c0[i] + c1[i];
}

// ---------------- launch ----------------

extern "C" void kernel_launch(void* const* d_in, const int* in_sizes, int n_in,
                              void* d_out, int out_size, void* d_ws, size_t ws_size,
                              hipStream_t stream)
{
    (void)in_sizes; (void)n_in; (void)out_size; (void)ws_size;
    const float* x  = (const float*)d_in[0];
    const float* Wr = (const float*)d_in[1];
    const float* W1 = (const float*)d_in[2];
    const float* b1 = (const float*)d_in[3];
    const float* Wg = (const float*)d_in[4];
    const float* bg = (const float*)d_in[5];
    const float* W2 = (const float*)d_in[6];
    const float* b2 = (const float*)d_in[7];
    float* out = (float*)d_out;

    char* ws = (char*)d_ws;
    u16* xbf = (u16*)ws;             ws += (size_t)T_TOK * D_DIM * sizeof(u16);
    u16* w2t = (u16*)ws;             ws += (size_t)E_EXP * D_DIM * FF_DIM * sizeof(u16);
    u16* hg = (u16*)ws;              ws += (size_t)NROWS * FF_DIM * sizeof(u16);
    float* contrib = (float*)ws;     ws += (size_t)2 * T_TOK * D_DIM * sizeof(float);
    int* tok_e = (int*)ws;           ws += (size_t)T_TOK * 2 * sizeof(int);
    float* tok_w = (float*)ws;       ws += (size_t)T_TOK * 2 * sizeof(float);
    int* row_token = (int*)ws;       ws += (size_t)NROWS * sizeof(int);
    int* row_slot = (int*)ws;        ws += (size_t)NROWS * sizeof(int);
    float* row_weight = (float*)ws;  ws += (size_t)NROWS * sizeof(float);
    int* cnt = (int*)ws;             ws += 8 * sizeof(int);
    int* basep = (int*)ws;           ws += 8 * sizeof(int);
    int* cursor = (int*)ws;          ws += 8 * sizeof(int);
    float* probsum = (float*)ws;     ws += 8 * sizeof(float);
    int* nt1 = (int*)ws;             ws += sizeof(int);
    int* nt2 = (int*)ws;             ws += sizeof(int);
    int* te1 = (int*)ws;             ws += MAXT1 * sizeof(int);
    int* tm1 = (int*)ws;             ws += MAXT1 * sizeof(int);
    int* te2 = (int*)ws;             ws += MAXT2 * sizeof(int);
    int* tm2 = (int*)ws;             ws += MAXT2 * sizeof(int);

    k_init<<<1, 64, 0, stream>>>(cnt, probsum);
    k_cvt_x<<<(T_TOK * D_DIM / 8) / 256, 256, 0, stream>>>(x, xbf);
    k_router<<<T_TOK / 4, 256, 0, stream>>>(x, Wr, tok_e, tok_w, cnt, probsum);
    k_prefix<<<1, 64, 0, stream>>>(cnt, probsum, basep, cursor, out + (size_t)T_TOK * D_DIM,
                                   nt1, te1, tm1, nt2, te2, tm2);
    k_assign<<<T_TOK / 256, 256, 0, stream>>>(tok_e, tok_w, basep, cursor, row_token, row_slot, row_weight);
    k_pass1<<<dim3(FF_DIM / 128, MAXT1), 512, 0, stream>>>(xbf, W1, Wg, b1, bg, W2, w2t, cnt, basep, row_token,
                                                           nt1, te1, tm1, hg);
    k_pass2<<<dim3(D_DIM / 128, MAXT2), 256, 0, stream>>>(hg, w2t, b2, cnt, basep, row_token, row_slot, row_weight,
                                                          nt2, te2, tm2, contrib);
    k_combine<<<(T_TOK * D_DIM / 4) / 256, 256, 0, stream>>>(contrib, out);
}

// Round 21
// 467.442 us; speedup vs baseline: 1.0086x; 1.0086x over previous
//
#include <hip/hip_runtime.h>
#include <hip/hip_bf16.h>
#include <math.h>

#define T_TOK 4096
#define D_DIM 1024
#define E_EXP 8
#define FF_DIM 4096
#define NROWS (T_TOK * 2)
#define MAXT1 40   // max m-tiles (BM=256): 8192/256 + 8
#define MAXT2 72   // max m-tiles (BM=128): 8192/128 + 8

typedef unsigned short u16;
typedef unsigned int u32;
typedef __attribute__((ext_vector_type(8))) short bf16x8;
typedef __attribute__((ext_vector_type(4))) float f32x4;
typedef __attribute__((ext_vector_type(2))) unsigned int u32x2;
typedef __attribute__((ext_vector_type(4))) short s16x4;

__device__ __forceinline__ u16 f2bf(float f) {
    union { float f; unsigned u; } v; v.f = f;
    unsigned r = v.u + 0x7FFFu + ((v.u >> 16) & 1u);
    return (u16)(r >> 16);
}

typedef const __attribute__((address_space(1))) u32* gas1_t;
typedef __attribute__((address_space(3))) u32* las3_t;
#define GLOAD16(g, l) __builtin_amdgcn_global_load_lds((gas1_t)(const void*)(g), (las3_t)(void*)(l), 16, 0, 0)
#define MFMA(a, b, c) __builtin_amdgcn_mfma_f32_16x16x32_bf16((a), (b), (c), 0, 0, 0)
#define CVTPK(dst, lo, hi) asm("v_cvt_pk_bf16_f32 %0, %1, %2" : "=v"(dst) : "v"(lo), "v"(hi))
#define CFENCE() asm volatile("" ::: "memory")
// B-tile swizzle for fused pass1: sigma(row) = (row ^ (row>>2)) & 7.
#define SIGB(r) (((r) ^ ((r) >> 2)) & 7)

// ---------------- small kernels ----------------

__global__ void k_init(int* cnt, float* probsum) {
    int i = threadIdx.x;
    if (i < E_EXP) { cnt[i] = 0; probsum[i] = 0.f; }
}

__global__ __launch_bounds__(256) void k_router(
    const float* __restrict__ x, const float* __restrict__ Wr,
    int* __restrict__ tok_e, float* __restrict__ tok_w,
    int* __restrict__ cnt, float* __restrict__ probsum)
{
    __shared__ float bp[E_EXP];
    __shared__ int   bc[E_EXP];
    const int tid = threadIdx.x;
    if (tid < E_EXP) { bp[tid] = 0.f; bc[tid] = 0; }
    __syncthreads();
    const int wave = tid >> 6, lane = tid & 63;
    const int t = blockIdx.x * 4 + wave;
    const float* xt = x + (size_t)t * D_DIM;
    float a[E_EXP] = {0.f,0.f,0.f,0.f,0.f,0.f,0.f,0.f};
    for (int j = lane; j < D_DIM; j += 64) {
        float xv = xt[j];
        #pragma unroll
        for (int e = 0; e < E_EXP; e++) a[e] = fmaf(xv, Wr[e * D_DIM + j], a[e]);
    }
    #pragma unroll
    for (int e = 0; e < E_EXP; e++) {
        #pragma unroll
        for (int off = 32; off; off >>= 1) a[e] += __shfl_xor(a[e], off, 64);
    }
    if (lane == 0) {
        float mx = a[0];
        #pragma unroll
        for (int e = 1; e < E_EXP; e++) mx = fmaxf(mx, a[e]);
        float p[E_EXP], s = 0.f;
        #pragma unroll
        for (int e = 0; e < E_EXP; e++) { p[e] = expf(a[e] - mx); s += p[e]; }
        float inv = 1.f / s;
        #pragma unroll
        for (int e = 0; e < E_EXP; e++) { p[e] *= inv; atomicAdd(&bp[e], p[e]); }
        int e0 = 0; float v0 = p[0];
        #pragma unroll
        for (int e = 1; e < E_EXP; e++) if (p[e] > v0) { v0 = p[e]; e0 = e; }
        int e1 = -1; float v1 = -1.f;
        #pragma unroll
        for (int e = 0; e < E_EXP; e++) if (e != e0 && p[e] > v1) { v1 = p[e]; e1 = e; }
        float sv = v0 + v1 + 1e-6f;
        tok_e[2*t] = e0; tok_e[2*t+1] = e1;
        tok_w[2*t] = v0 / sv; tok_w[2*t+1] = v1 / sv;
        atomicAdd(&bc[e0], 1); atomicAdd(&bc[e1], 1);
    }
    __syncthreads();
    if (tid < E_EXP) { atomicAdd(&cnt[tid], bc[tid]); atomicAdd(&probsum[tid], bp[tid]); }
}

__global__ void k_prefix(const int* __restrict__ cnt, const float* __restrict__ probsum,
                         int* __restrict__ basep, int* __restrict__ cursor,
                         float* __restrict__ out_lb,
                         int* __restrict__ nt1, int* __restrict__ te1, int* __restrict__ tm1,
                         int* __restrict__ nt2, int* __restrict__ te2, int* __restrict__ tm2)
{
    if (threadIdx.x == 0) {
        int b = 0; float lb = 0.f;
        for (int e = 0; e < E_EXP; e++) {
            basep[e] = b; b += cnt[e];
            lb += ((float)cnt[e] / (8192.f + 1e-6f)) * probsum[e];
        }
        *out_lb = lb * (float)E_EXP;
        int n1 = 0, n2 = 0;
        for (int e = 0; e < E_EXP; e++) {
            for (int m = 0; m < cnt[e]; m += 256) { te1[n1] = e; tm1[n1] = m; n1++; }
            for (int m = 0; m < cnt[e]; m += 128) { te2[n2] = e; tm2[n2] = m; n2++; }
        }
        *nt1 = n1; *nt2 = n2;
    }
    if (threadIdx.x < E_EXP) cursor[threadIdx.x] = 0;
}

__global__ void k_assign(const int* __restrict__ tok_e, const float* __restrict__ tok_w,
                         const int* __restrict__ basep, int* __restrict__ cursor,
                         int* __restrict__ row_token, int* __restrict__ row_slot,
                         float* __restrict__ row_weight)
{
    int t = blockIdx.x * blockDim.x + threadIdx.x;
    if (t >= T_TOK) return;
    #pragma unroll
    for (int k = 0; k < 2; k++) {
        int e = tok_e[2*t + k];
        int pos = basep[e] + atomicAdd(&cursor[e], 1);
        row_token[pos] = t; row_slot[pos] = k; row_weight[pos] = tok_w[2*t + k];
    }
}

__global__ __launch_bounds__(256) void k_cvt_x(const float* __restrict__ in, u16* __restrict__ out) {
    size_t i = ((size_t)blockIdx.x * 256 + threadIdx.x) * 8;
    f32x4 a = *(const f32x4*)(in + i);
    f32x4 b = *(const f32x4*)(in + i + 4);
    bf16x8 o;
    #pragma unroll
    for (int j = 0; j < 4; j++) { o[j] = (short)f2bf(a[j]); o[j + 4] = (short)f2bf(b[j]); }
    *(bf16x8*)(out + i) = o;
}

// W2 prepass: fp32 [E][FF][D] -> bf16 [E][D][FF] (tile transpose)
__global__ __launch_bounds__(256) void k_cvt_w2(const float* __restrict__ W2, u16* __restrict__ w2t) {
    __shared__ u16 t[64][68];
    const float* in = W2 + (size_t)blockIdx.z * FF_DIM * D_DIM;
    u16* out = w2t + (size_t)blockIdx.z * FF_DIM * D_DIM;
    const int R = FF_DIM, C = D_DIM;
    const int r0 = blockIdx.y * 64, c0 = blockIdx.x * 64;
    const int tid = threadIdx.x;
    const int lr = tid >> 4, lc = (tid & 15) * 4;
    #pragma unroll
    for (int i = 0; i < 4; i++) {
        const int r = lr + i * 16;
        f32x4 v = *(const f32x4*)(in + (size_t)(r0 + r) * C + c0 + lc);
        s16x4 w;
        #pragma unroll
        for (int j = 0; j < 4; j++) w[j] = (short)f2bf(v[j]);
        *(s16x4*)&t[r][lc] = w;
    }
    __syncthreads();
    #pragma unroll
    for (int i = 0; i < 4; i++) {
        const int c = lr + i * 16;
        s16x4 w;
        #pragma unroll
        for (int j = 0; j < 4; j++) w[j] = (short)t[lc + j][c];
        *(s16x4*)(out + (size_t)(c0 + c) * R + r0 + lc) = w;
    }
}

// ---------------- pass 1: hg = silu(x@Wg) * (x@W1) ----------------
// R17/R19 fused version: BM=256 BN=128 BK=64, 8 waves; W1/Wg consumed fp32 from
// [E][D][FF] with in-kernel transpose-convert (cvt_pk + b64 writes, SIGB swizzle);
// A (xbf bf16) via global_load_lds. One drain+barrier per K-tile.

__global__ __launch_bounds__(512, 2) void k_pass1(
    const u16* __restrict__ xbf,
    const float* __restrict__ W1, const float* __restrict__ Wg,
    const float* __restrict__ b1v, const float* __restrict__ bgv,
    const int* __restrict__ cnt, const int* __restrict__ basep,
    const int* __restrict__ row_token,
    const int* __restrict__ ntp, const int* __restrict__ te, const int* __restrict__ tm,
    u16* __restrict__ hg)
{
    const int ty = blockIdx.y;
    if (ty >= *ntp) return;
    const int e = te[ty];
    const int m0 = tm[ty];
    const int count = cnt[e];
    const int rbase = basep[e];
    const int n0 = blockIdx.x * 128;

    __shared__ __align__(16) u16 LDS[2 * 32768];

    const int tid = threadIdx.x;
    const int l = tid & 63;
    const int w = tid >> 6;

    const int rb = tid >> 3;
    const int swA = ((tid & 7) ^ ((tid >> 3) & 7)) * 8;
    const u16* sA[4];
    #pragma unroll
    for (int s = 0; s < 4; s++) {
        int g = m0 + rb + s * 64; if (g > count - 1) g = count - 1;
        sA[s] = xbf + (size_t)row_token[rbase + g] * D_DIM + swA;
    }

    const int nq = tid & 31;
    const int kq = tid >> 5;
    const float* pBh = W1 + ((size_t)e * D_DIM + kq * 4) * FF_DIM + n0 + nq * 4;
    const float* pBg = Wg + ((size_t)e * D_DIM + kq * 4) * FF_DIM + n0 + nq * 4;
    const int cW = kq >> 1;
    const int offW = (kq & 1) * 4;
    int wdst[4];
    #pragma unroll
    for (int j = 0; j < 4; j++) {
        const int row = nq * 4 + j;
        wdst[j] = row * 64 + (cW ^ SIGB(row)) * 8 + offW;
    }

    const int wm = w >> 2, wn = w & 3;
    const int fr = l & 15, q = l >> 4;
    const int s7 = fr & 7;

    f32x4 acc_h[8][2], acc_g[8][2];
    const f32x4 z4 = {0.f, 0.f, 0.f, 0.f};
    #pragma unroll
    for (int mf = 0; mf < 8; mf++)
        #pragma unroll
        for (int nf = 0; nf < 2; nf++) { acc_h[mf][nf] = z4; acc_g[mf][nf] = z4; }

    f32x4 vb0, vb1, vb2, vb3;

    #define LOADB1(P, K0) do { \
        const float* p_ = (P) + (size_t)(K0) * FF_DIM; \
        vb0 = *(const f32x4*)(p_); \
        vb1 = *(const f32x4*)(p_ + FF_DIM); \
        vb2 = *(const f32x4*)(p_ + 2 * FF_DIM); \
        vb3 = *(const f32x4*)(p_ + 3 * FF_DIM); \
    } while (0)

    #define CVTW1(BASE) do { \
        _Pragma("unroll") \
        for (int j = 0; j < 4; j++) { \
            u32 lo_, hi_; u32x2 wv_; \
            CVTPK(lo_, vb0[j], vb1[j]); \
            CVTPK(hi_, vb2[j], vb3[j]); \
            wv_.x = lo_; wv_.y = hi_; \
            *(u32x2*)&LDS[(BASE) + wdst[j]] = wv_; \
        } \
    } while (0)

    #define STAGE_A1(B, K0) do { \
        _Pragma("unroll") \
        for (int s = 0; s < 4; s++) \
            GLOAD16(sA[s] + (K0), &LDS[(B) * 32768 + s * 4096 + tid * 8]); \
    } while (0)

    auto COMP = [&](int kk, int ab) {
        const int rsA = ((kk * 4 + q) ^ s7) * 8;
        const int rB0 = wn * 32 + fr, rB1 = wn * 32 + 16 + fr;
        const int cb0 = ((kk * 4 + q) ^ SIGB(rB0)) * 8;
        const int cb1 = ((kk * 4 + q) ^ SIGB(rB1)) * 8;
        bf16x8 bh0 = *(const bf16x8*)&LDS[ab + 16384 + rB0 * 64 + cb0];
        bf16x8 bg0 = *(const bf16x8*)&LDS[ab + 24576 + rB0 * 64 + cb0];
        bf16x8 bh1 = *(const bf16x8*)&LDS[ab + 16384 + rB1 * 64 + cb1];
        bf16x8 bg1 = *(const bf16x8*)&LDS[ab + 24576 + rB1 * 64 + cb1];
        #define LDA1(i) (*(const bf16x8*)&LDS[ab + (wm * 128 + (i) * 16 + fr) * 64 + rsA])
        #define MF4(areg, i) do { \
            __builtin_amdgcn_s_setprio(1); \
            acc_h[i][0] = MFMA(areg, bh0, acc_h[i][0]); \
            acc_h[i][1] = MFMA(areg, bh1, acc_h[i][1]); \
            acc_g[i][0] = MFMA(areg, bg0, acc_g[i][0]); \
            acc_g[i][1] = MFMA(areg, bg1, acc_g[i][1]); \
            __builtin_amdgcn_s_setprio(0); } while (0)
        bf16x8 aA = LDA1(0);
        bf16x8 aB = LDA1(1);
        bf16x8 aC;
        aC = LDA1(2); MF4(aA, 0);
        aA = LDA1(3); MF4(aB, 1);
        aB = LDA1(4); MF4(aC, 2);
        aC = LDA1(5); MF4(aA, 3);
        aA = LDA1(6); MF4(aB, 4);
        aB = LDA1(7); MF4(aC, 5);
        MF4(aA, 6);
        MF4(aB, 7);
        #undef LDA1
        #undef MF4
    };

    const int NT = D_DIM / 64;   // 16
    LOADB1(pBh, 0);
    CVTW1(0 + 16384);
    STAGE_A1(0, 0);
    LOADB1(pBg, 0);
    CVTW1(0 + 24576);
    asm volatile("s_waitcnt vmcnt(0) lgkmcnt(0)" ::: "memory");
    __builtin_amdgcn_s_barrier();
    CFENCE();

    int b = 0;
    #pragma unroll 1
    for (int t = 0; t < NT; ++t) {
        const int ab = b * 32768;
        const int nboff = (b ^ 1) * 32768;
        const int kN = (t + 1 < NT ? t + 1 : NT - 1) * 64;
        LOADB1(pBh, kN);
        COMP(0, ab);
        CVTW1(nboff + 16384);
        STAGE_A1(b ^ 1, kN);
        LOADB1(pBg, kN);
        COMP(1, ab);
        CVTW1(nboff + 24576);
        asm volatile("s_waitcnt vmcnt(0) lgkmcnt(0)" ::: "memory");
        __builtin_amdgcn_s_barrier();
        CFENCE();
        b ^= 1;
    }
    asm volatile("s_waitcnt vmcnt(0)" ::: "memory");
    #undef LOADB1
    #undef CVTW1
    #undef STAGE_A1

    const float* b1p = b1v + (size_t)e * FF_DIM + n0;
    const float* bgp = bgv + (size_t)e * FF_DIM + n0;
    #pragma unroll
    for (int mf = 0; mf < 8; mf++) {
        const int rl = wm * 128 + mf * 16 + q * 4;
        #pragma unroll
        for (int r = 0; r < 4; r++) {
            const int g = m0 + rl + r;
            if (g < count) {
                u16* orow = hg + (size_t)(rbase + g) * FF_DIM + n0;
                #pragma unroll
                for (int nf = 0; nf < 2; nf++) {
                    const int col = wn * 32 + nf * 16 + fr;
                    float hv = acc_h[mf][nf][r] + b1p[col];
                    float gv = acc_g[mf][nf][r] + bgp[col];
                    float sig = 1.f / (1.f + expf(-gv));
                    orow[col] = f2bf(gv * sig * hv);
                }
            }
        }
    }
}

// ---------------- pass 2: contrib[slot] = w * (hg @ W2 + b2) ----------------
// R11/R17 config: BM=128 BN=128 BK=64, 4 waves (2Mx2N, 64x64/wave),
// 2x32KB dbuf -> 2 blocks/CU, depth-1 counted vmcnt(8), sigma(r)=r&7 swizzle,
// both operands bf16 via global_load_lds (w2t prepass).

__global__ __launch_bounds__(256, 2) void k_pass2(
    const u16* __restrict__ hg,
    const u16* __restrict__ w2t, const float* __restrict__ b2v,
    const int* __restrict__ cnt, const int* __restrict__ basep,
    const int* __restrict__ row_token, const int* __restrict__ row_slot,
    const float* __restrict__ row_weight,
    const int* __restrict__ ntp, const int* __restrict__ te, const int* __restrict__ tm,
    float* __restrict__ contrib)
{
    const int ty = blockIdx.y;
    if (ty >= *ntp) return;
    const int e = te[ty];
    const int m0 = tm[ty];
    const int count = cnt[e];
    const int rbase = basep[e];
    const int n0 = blockIdx.x * 128;

    __shared__ __align__(16) u16 LDS[2 * 16384];

    const int tid = threadIdx.x;
    const int l = tid & 63;
    const int w = tid >> 6;

    const int rb = tid >> 3;                        // 0..31
    const int sw0 = ((tid & 7) ^ ((tid >> 3) & 7)) * 8;
    const u16* sA[4];
    #pragma unroll
    for (int s = 0; s < 4; s++) {
        int g = m0 + rb + s * 32; if (g > count - 1) g = count - 1;
        sA[s] = hg + (size_t)(rbase + g) * FF_DIM + sw0;
    }
    const u16* sB[4];
    #pragma unroll
    for (int s = 0; s < 4; s++)
        sB[s] = w2t + ((size_t)e * D_DIM + (size_t)(n0 + rb + s * 32)) * FF_DIM + sw0;

    const int wm = w >> 1, wn = w & 1;   // 2M x 2N
    const int fr = l & 15, q = l >> 4;
    const int s7 = fr & 7;

    f32x4 acc[4][4];
    const f32x4 z4 = {0.f, 0.f, 0.f, 0.f};
    #pragma unroll
    for (int mf = 0; mf < 4; mf++)
        #pragma unroll
        for (int nf = 0; nf < 4; nf++) acc[mf][nf] = z4;

    auto STAGE = [&](int b, int k0) {
        #pragma unroll
        for (int s = 0; s < 4; s++)
            GLOAD16(sA[s] + k0, &LDS[b * 16384 + s * 2048 + tid * 8]);
        #pragma unroll
        for (int s = 0; s < 4; s++)
            GLOAD16(sB[s] + k0, &LDS[b * 16384 + 8192 + s * 2048 + tid * 8]);
    };

    const int NT = FF_DIM / 64;   // 64
    STAGE(0, 0);
    int cur = 0;
    #pragma unroll 1
    for (int t = 0; t < NT; ++t) {
        if (t + 1 < NT) {
            STAGE(cur ^ 1, (t + 1) * 64);
            asm volatile("s_waitcnt vmcnt(8)" ::: "memory");
        } else {
            asm volatile("s_waitcnt vmcnt(0)" ::: "memory");
        }
        __builtin_amdgcn_s_barrier();
        CFENCE();
        const int ab = cur * 16384;
        #pragma unroll
        for (int kk = 0; kk < 2; kk++) {
            const int rs = ((kk * 4 + q) ^ s7) * 8;
            bf16x8 a[4], bb[4];
            #pragma unroll
            for (int mf = 0; mf < 4; mf++)
                a[mf] = *(const bf16x8*)&LDS[ab + (wm * 64 + mf * 16 + fr) * 64 + rs];
            #pragma unroll
            for (int nf = 0; nf < 4; nf++)
                bb[nf] = *(const bf16x8*)&LDS[ab + 8192 + (wn * 64 + nf * 16 + fr) * 64 + rs];
            __builtin_amdgcn_s_setprio(1);
            #pragma unroll
            for (int mf = 0; mf < 4; mf++)
                #pragma unroll
                for (int nf = 0; nf < 4; nf++)
                    acc[mf][nf] = MFMA(a[mf], bb[nf], acc[mf][nf]);
            __builtin_amdgcn_s_setprio(0);
        }
        CFENCE();
        __builtin_amdgcn_s_barrier();
        cur ^= 1;
    }

    const float* b2p = b2v + (size_t)e * D_DIM + n0;
    #pragma unroll
    for (int mf = 0; mf < 4; mf++) {
        const int rl = wm * 64 + mf * 16 + q * 4;
        #pragma unroll
        for (int r = 0; r < 4; r++) {
            const int g = m0 + rl + r;
            if (g < count) {
                const int token = row_token[rbase + g];
                const int slot  = row_slot[rbase + g];
                const float wgt_ = row_weight[rbase + g];
                float* orow = contrib + ((size_t)slot * T_TOK + token) * D_DIM + n0;
                #pragma unroll
                for (int nf = 0; nf < 4; nf++) {
                    const int col = wn * 64 + nf * 16 + fr;
                    orow[col] = wgt_ * (acc[mf][nf][r] + b2p[col]);
                }
            }
        }
    }
}

__global__ void k_combine(const float* __restrict__ contrib, float* __restrict__ out) {
    int i = blockIdx.x * blockDim.x + threadIdx.x;
    const f32x4* c0 = (const f32x4*)contrib;
    const f32x4* c1 = c0 + ((size_t)T_TOK * D_DIM / 4);
    f32x4* o = (f32x4*)out;
    o[i] = c0[i] + c1[i];
}

// ---------------- launch ----------------

extern "C" void kernel_launch(void* const* d_in, const int* in_sizes, int n_in,
                              void* d_out, int out_size, void* d_ws, size_t ws_size,
                              hipStream_t stream)
{
    (void)in_sizes; (void)n_in; (void)out_size; (void)ws_size;
    const float* x  = (const float*)d_in[0];
    const float* Wr = (const float*)d_in[1];
    const float* W1 = (const float*)d_in[2];
    const float* b1 = (const float*)d_in[3];
    const float* Wg = (const float*)d_in[4];
    const float* bg = (const float*)d_in[5];
    const float* W2 = (const float*)d_in[6];
    const float* b2 = (const float*)d_in[7];
    float* out = (float*)d_out;

    char* ws = (char*)d_ws;
    u16* xbf = (u16*)ws;             ws += (size_t)T_TOK * D_DIM * sizeof(u16);
    u16* w2t = (u16*)ws;             ws += (size_t)E_EXP * D_DIM * FF_DIM * sizeof(u16);
    u16* hg = (u16*)ws;              ws += (size_t)NROWS * FF_DIM * sizeof(u16);
    float* contrib = (float*)ws;     ws += (size_t)2 * T_TOK * D_DIM * sizeof(float);
    int* tok_e = (int*)ws;           ws += (size_t)T_TOK * 2 * sizeof(int);
    float* tok_w = (float*)ws;       ws += (size_t)T_TOK * 2 * sizeof(float);
    int* row_token = (int*)ws;       ws += (size_t)NROWS * sizeof(int);
    int* row_slot = (int*)ws;        ws += (size_t)NROWS * sizeof(int);
    float* row_weight = (float*)ws;  ws += (size_t)NROWS * sizeof(float);
    int* cnt = (int*)ws;             ws += 8 * sizeof(int);
    int* basep = (int*)ws;           ws += 8 * sizeof(int);
    int* cursor = (int*)ws;          ws += 8 * sizeof(int);
    float* probsum = (float*)ws;     ws += 8 * sizeof(float);
    int* nt1 = (int*)ws;             ws += sizeof(int);
    int* nt2 = (int*)ws;             ws += sizeof(int);
    int* te1 = (int*)ws;             ws += MAXT1 * sizeof(int);
    int* tm1 = (int*)ws;             ws += MAXT1 * sizeof(int);
    int* te2 = (int*)ws;             ws += MAXT2 * sizeof(int);
    int* tm2 = (int*)ws;             ws += MAXT2 * sizeof(int);

    k_init<<<1, 64, 0, stream>>>(cnt, probsum);
    k_cvt_x<<<(T_TOK * D_DIM / 8) / 256, 256, 0, stream>>>(x, xbf);
    k_cvt_w2<<<dim3(D_DIM / 64, FF_DIM / 64, E_EXP), 256, 0, stream>>>(W2, w2t);
    k_router<<<T_TOK / 4, 256, 0, stream>>>(x, Wr, tok_e, tok_w, cnt, probsum);
    k_prefix<<<1, 64, 0, stream>>>(cnt, probsum, basep, cursor, out + (size_t)T_TOK * D_DIM,
                                   nt1, te1, tm1, nt2, te2, tm2);
    k_assign<<<T_TOK / 256, 256, 0, stream>>>(tok_e, tok_w, basep, cursor, row_token, row_slot, row_weight);
    k_pass1<<<dim3(FF_DIM / 128, MAXT1), 512, 0, stream>>>(xbf, W1, Wg, b1, bg, cnt, basep, row_token,
                                                           nt1, te1, tm1, hg);
    k_pass2<<<dim3(D_DIM / 128, MAXT2), 256, 0, stream>>>(hg, w2t, b2, cnt, basep, row_token, row_slot, row_weight,
                                                          nt2, te2, tm2, contrib);
    k_combine<<<(T_TOK * D_DIM / 4) / 256, 256, 0, stream>>>(contrib, out);
}

// Round 22
// 460.039 us; speedup vs baseline: 1.0248x; 1.0161x over previous
//
#include <hip/hip_runtime.h>
#include <hip/hip_bf16.h>
#include <math.h>

#define T_TOK 4096
#define D_DIM 1024
#define E_EXP 8
#define FF_DIM 4096
#define NROWS (T_TOK * 2)
#define MAXT1 40   // max m-tiles (BM=256): 8192/256 + 8
#define MAXT2 72   // max m-tiles (BM=128): 8192/128 + 8

typedef unsigned short u16;
typedef unsigned int u32;
typedef __attribute__((ext_vector_type(8))) short bf16x8;
typedef __attribute__((ext_vector_type(4))) float f32x4;
typedef __attribute__((ext_vector_type(2))) unsigned int u32x2;
typedef __attribute__((ext_vector_type(4))) short s16x4;

__device__ __forceinline__ u16 f2bf(float f) {
    union { float f; unsigned u; } v; v.f = f;
    unsigned r = v.u + 0x7FFFu + ((v.u >> 16) & 1u);
    return (u16)(r >> 16);
}

typedef const __attribute__((address_space(1))) u32* gas1_t;
typedef __attribute__((address_space(3))) u32* las3_t;
#define GLOAD16(g, l) __builtin_amdgcn_global_load_lds((gas1_t)(const void*)(g), (las3_t)(void*)(l), 16, 0, 0)
#define MFMA(a, b, c) __builtin_amdgcn_mfma_f32_16x16x32_bf16((a), (b), (c), 0, 0, 0)
#define CVTPK(dst, lo, hi) asm("v_cvt_pk_bf16_f32 %0, %1, %2" : "=v"(dst) : "v"(lo), "v"(hi))
#define CFENCE() asm volatile("" ::: "memory")
// B-tile swizzle for fused pass1: sigma(row) = (row ^ (row>>2)) & 7.
#define SIGB(r) (((r) ^ ((r) >> 2)) & 7)

// ---------------- small kernels ----------------

// Router + x->bf16 conversion fused: the router loop already touches every x
// element once; add the bf16 store to produce xbf in the same pass.
__global__ __launch_bounds__(256) void k_router(
    const float* __restrict__ x, const float* __restrict__ Wr,
    u16* __restrict__ xbf,
    int* __restrict__ tok_e, float* __restrict__ tok_w,
    int* __restrict__ cnt, float* __restrict__ probsum)
{
    __shared__ float bp[E_EXP];
    __shared__ int   bc[E_EXP];
    const int tid = threadIdx.x;
    if (tid < E_EXP) { bp[tid] = 0.f; bc[tid] = 0; }
    __syncthreads();
    const int wave = tid >> 6, lane = tid & 63;
    const int t = blockIdx.x * 4 + wave;
    const float* xt = x + (size_t)t * D_DIM;
    u16* xo = xbf + (size_t)t * D_DIM;
    float a[E_EXP] = {0.f,0.f,0.f,0.f,0.f,0.f,0.f,0.f};
    for (int j = lane; j < D_DIM; j += 64) {
        float xv = xt[j];
        xo[j] = f2bf(xv);
        #pragma unroll
        for (int e = 0; e < E_EXP; e++) a[e] = fmaf(xv, Wr[e * D_DIM + j], a[e]);
    }
    #pragma unroll
    for (int e = 0; e < E_EXP; e++) {
        #pragma unroll
        for (int off = 32; off; off >>= 1) a[e] += __shfl_xor(a[e], off, 64);
    }
    if (lane == 0) {
        float mx = a[0];
        #pragma unroll
        for (int e = 1; e < E_EXP; e++) mx = fmaxf(mx, a[e]);
        float p[E_EXP], s = 0.f;
        #pragma unroll
        for (int e = 0; e < E_EXP; e++) { p[e] = expf(a[e] - mx); s += p[e]; }
        float inv = 1.f / s;
        #pragma unroll
        for (int e = 0; e < E_EXP; e++) { p[e] *= inv; atomicAdd(&bp[e], p[e]); }
        int e0 = 0; float v0 = p[0];
        #pragma unroll
        for (int e = 1; e < E_EXP; e++) if (p[e] > v0) { v0 = p[e]; e0 = e; }
        int e1 = -1; float v1 = -1.f;
        #pragma unroll
        for (int e = 0; e < E_EXP; e++) if (e != e0 && p[e] > v1) { v1 = p[e]; e1 = e; }
        float sv = v0 + v1 + 1e-6f;
        tok_e[2*t] = e0; tok_e[2*t+1] = e1;
        tok_w[2*t] = v0 / sv; tok_w[2*t+1] = v1 / sv;
        atomicAdd(&bc[e0], 1); atomicAdd(&bc[e1], 1);
    }
    __syncthreads();
    if (tid < E_EXP) { atomicAdd(&cnt[tid], bc[tid]); atomicAdd(&probsum[tid], bp[tid]); }
}

__global__ void k_prefix(const int* __restrict__ cnt, const float* __restrict__ probsum,
                         int* __restrict__ basep, int* __restrict__ cursor,
                         float* __restrict__ out_lb,
                         int* __restrict__ nt1, int* __restrict__ te1, int* __restrict__ tm1,
                         int* __restrict__ nt2, int* __restrict__ te2, int* __restrict__ tm2)
{
    if (threadIdx.x == 0) {
        int b = 0; float lb = 0.f;
        for (int e = 0; e < E_EXP; e++) {
            basep[e] = b; b += cnt[e];
            lb += ((float)cnt[e] / (8192.f + 1e-6f)) * probsum[e];
        }
        *out_lb = lb * (float)E_EXP;
        int n1 = 0, n2 = 0;
        for (int e = 0; e < E_EXP; e++) {
            for (int m = 0; m < cnt[e]; m += 256) { te1[n1] = e; tm1[n1] = m; n1++; }
            for (int m = 0; m < cnt[e]; m += 128) { te2[n2] = e; tm2[n2] = m; n2++; }
        }
        *nt1 = n1; *nt2 = n2;
    }
    if (threadIdx.x < E_EXP) cursor[threadIdx.x] = 0;
}

__global__ void k_assign(const int* __restrict__ tok_e, const float* __restrict__ tok_w,
                         const int* __restrict__ basep, int* __restrict__ cursor,
                         int* __restrict__ row_token, int* __restrict__ row_slot,
                         float* __restrict__ row_weight)
{
    int t = blockIdx.x * blockDim.x + threadIdx.x;
    if (t >= T_TOK) return;
    #pragma unroll
    for (int k = 0; k < 2; k++) {
        int e = tok_e[2*t + k];
        int pos = basep[e] + atomicAdd(&cursor[e], 1);
        row_token[pos] = t; row_slot[pos] = k; row_weight[pos] = tok_w[2*t + k];
    }
}

// W2 prepass: fp32 [E][FF][D] -> bf16 [E][D][FF] (tile transpose).
// Also zero-inits the router's counters (runs before k_router in stream order).
__global__ __launch_bounds__(256) void k_cvt_w2(const float* __restrict__ W2, u16* __restrict__ w2t,
                                                int* __restrict__ cnt, float* __restrict__ probsum) {
    __shared__ u16 t[64][68];
    if (blockIdx.x == 0 && blockIdx.y == 0 && blockIdx.z == 0 && threadIdx.x < E_EXP) {
        cnt[threadIdx.x] = 0; probsum[threadIdx.x] = 0.f;
    }
    const float* in = W2 + (size_t)blockIdx.z * FF_DIM * D_DIM;
    u16* out = w2t + (size_t)blockIdx.z * FF_DIM * D_DIM;
    const int R = FF_DIM, C = D_DIM;
    const int r0 = blockIdx.y * 64, c0 = blockIdx.x * 64;
    const int tid = threadIdx.x;
    const int lr = tid >> 4, lc = (tid & 15) * 4;
    #pragma unroll
    for (int i = 0; i < 4; i++) {
        const int r = lr + i * 16;
        f32x4 v = *(const f32x4*)(in + (size_t)(r0 + r) * C + c0 + lc);
        s16x4 w;
        #pragma unroll
        for (int j = 0; j < 4; j++) w[j] = (short)f2bf(v[j]);
        *(s16x4*)&t[r][lc] = w;
    }
    __syncthreads();
    #pragma unroll
    for (int i = 0; i < 4; i++) {
        const int c = lr + i * 16;
        s16x4 w;
        #pragma unroll
        for (int j = 0; j < 4; j++) w[j] = (short)t[lc + j][c];
        *(s16x4*)(out + (size_t)(c0 + c) * R + r0 + lc) = w;
    }
}

// ---------------- pass 1: hg = silu(x@Wg) * (x@W1) ----------------
// R17/R19/R21 fused version: BM=256 BN=128 BK=64, 8 waves; W1/Wg consumed fp32
// from [E][D][FF] with in-kernel transpose-convert (cvt_pk + b64 writes, SIGB
// swizzle); A (xbf bf16) via global_load_lds. One drain+barrier per K-tile.

__global__ __launch_bounds__(512, 2) void k_pass1(
    const u16* __restrict__ xbf,
    const float* __restrict__ W1, const float* __restrict__ Wg,
    const float* __restrict__ b1v, const float* __restrict__ bgv,
    const int* __restrict__ cnt, const int* __restrict__ basep,
    const int* __restrict__ row_token,
    const int* __restrict__ ntp, const int* __restrict__ te, const int* __restrict__ tm,
    u16* __restrict__ hg)
{
    const int ty = blockIdx.y;
    if (ty >= *ntp) return;
    const int e = te[ty];
    const int m0 = tm[ty];
    const int count = cnt[e];
    const int rbase = basep[e];
    const int n0 = blockIdx.x * 128;

    __shared__ __align__(16) u16 LDS[2 * 32768];

    const int tid = threadIdx.x;
    const int l = tid & 63;
    const int w = tid >> 6;

    const int rb = tid >> 3;
    const int swA = ((tid & 7) ^ ((tid >> 3) & 7)) * 8;
    const u16* sA[4];
    #pragma unroll
    for (int s = 0; s < 4; s++) {
        int g = m0 + rb + s * 64; if (g > count - 1) g = count - 1;
        sA[s] = xbf + (size_t)row_token[rbase + g] * D_DIM + swA;
    }

    const int nq = tid & 31;
    const int kq = tid >> 5;
    const float* pBh = W1 + ((size_t)e * D_DIM + kq * 4) * FF_DIM + n0 + nq * 4;
    const float* pBg = Wg + ((size_t)e * D_DIM + kq * 4) * FF_DIM + n0 + nq * 4;
    const int cW = kq >> 1;
    const int offW = (kq & 1) * 4;
    int wdst[4];
    #pragma unroll
    for (int j = 0; j < 4; j++) {
        const int row = nq * 4 + j;
        wdst[j] = row * 64 + (cW ^ SIGB(row)) * 8 + offW;
    }

    const int wm = w >> 2, wn = w & 3;
    const int fr = l & 15, q = l >> 4;
    const int s7 = fr & 7;

    f32x4 acc_h[8][2], acc_g[8][2];
    const f32x4 z4 = {0.f, 0.f, 0.f, 0.f};
    #pragma unroll
    for (int mf = 0; mf < 8; mf++)
        #pragma unroll
        for (int nf = 0; nf < 2; nf++) { acc_h[mf][nf] = z4; acc_g[mf][nf] = z4; }

    f32x4 vb0, vb1, vb2, vb3;

    #define LOADB1(P, K0) do { \
        const float* p_ = (P) + (size_t)(K0) * FF_DIM; \
        vb0 = *(const f32x4*)(p_); \
        vb1 = *(const f32x4*)(p_ + FF_DIM); \
        vb2 = *(const f32x4*)(p_ + 2 * FF_DIM); \
        vb3 = *(const f32x4*)(p_ + 3 * FF_DIM); \
    } while (0)

    #define CVTW1(BASE) do { \
        _Pragma("unroll") \
        for (int j = 0; j < 4; j++) { \
            u32 lo_, hi_; u32x2 wv_; \
            CVTPK(lo_, vb0[j], vb1[j]); \
            CVTPK(hi_, vb2[j], vb3[j]); \
            wv_.x = lo_; wv_.y = hi_; \
            *(u32x2*)&LDS[(BASE) + wdst[j]] = wv_; \
        } \
    } while (0)

    #define STAGE_A1(B, K0) do { \
        _Pragma("unroll") \
        for (int s = 0; s < 4; s++) \
            GLOAD16(sA[s] + (K0), &LDS[(B) * 32768 + s * 4096 + tid * 8]); \
    } while (0)

    auto COMP = [&](int kk, int ab) {
        const int rsA = ((kk * 4 + q) ^ s7) * 8;
        const int rB0 = wn * 32 + fr, rB1 = wn * 32 + 16 + fr;
        const int cb0 = ((kk * 4 + q) ^ SIGB(rB0)) * 8;
        const int cb1 = ((kk * 4 + q) ^ SIGB(rB1)) * 8;
        bf16x8 bh0 = *(const bf16x8*)&LDS[ab + 16384 + rB0 * 64 + cb0];
        bf16x8 bg0 = *(const bf16x8*)&LDS[ab + 24576 + rB0 * 64 + cb0];
        bf16x8 bh1 = *(const bf16x8*)&LDS[ab + 16384 + rB1 * 64 + cb1];
        bf16x8 bg1 = *(const bf16x8*)&LDS[ab + 24576 + rB1 * 64 + cb1];
        #define LDA1(i) (*(const bf16x8*)&LDS[ab + (wm * 128 + (i) * 16 + fr) * 64 + rsA])
        #define MF4(areg, i) do { \
            __builtin_amdgcn_s_setprio(1); \
            acc_h[i][0] = MFMA(areg, bh0, acc_h[i][0]); \
            acc_h[i][1] = MFMA(areg, bh1, acc_h[i][1]); \
            acc_g[i][0] = MFMA(areg, bg0, acc_g[i][0]); \
            acc_g[i][1] = MFMA(areg, bg1, acc_g[i][1]); \
            __builtin_amdgcn_s_setprio(0); } while (0)
        bf16x8 aA = LDA1(0);
        bf16x8 aB = LDA1(1);
        bf16x8 aC;
        aC = LDA1(2); MF4(aA, 0);
        aA = LDA1(3); MF4(aB, 1);
        aB = LDA1(4); MF4(aC, 2);
        aC = LDA1(5); MF4(aA, 3);
        aA = LDA1(6); MF4(aB, 4);
        aB = LDA1(7); MF4(aC, 5);
        MF4(aA, 6);
        MF4(aB, 7);
        #undef LDA1
        #undef MF4
    };

    const int NT = D_DIM / 64;   // 16
    LOADB1(pBh, 0);
    CVTW1(0 + 16384);
    STAGE_A1(0, 0);
    LOADB1(pBg, 0);
    CVTW1(0 + 24576);
    asm volatile("s_waitcnt vmcnt(0) lgkmcnt(0)" ::: "memory");
    __builtin_amdgcn_s_barrier();
    CFENCE();

    int b = 0;
    #pragma unroll 1
    for (int t = 0; t < NT; ++t) {
        const int ab = b * 32768;
        const int nboff = (b ^ 1) * 32768;
        const int kN = (t + 1 < NT ? t + 1 : NT - 1) * 64;
        LOADB1(pBh, kN);
        COMP(0, ab);
        CVTW1(nboff + 16384);
        STAGE_A1(b ^ 1, kN);
        LOADB1(pBg, kN);
        COMP(1, ab);
        CVTW1(nboff + 24576);
        asm volatile("s_waitcnt vmcnt(0) lgkmcnt(0)" ::: "memory");
        __builtin_amdgcn_s_barrier();
        CFENCE();
        b ^= 1;
    }
    asm volatile("s_waitcnt vmcnt(0)" ::: "memory");
    #undef LOADB1
    #undef CVTW1
    #undef STAGE_A1

    const float* b1p = b1v + (size_t)e * FF_DIM + n0;
    const float* bgp = bgv + (size_t)e * FF_DIM + n0;
    #pragma unroll
    for (int mf = 0; mf < 8; mf++) {
        const int rl = wm * 128 + mf * 16 + q * 4;
        #pragma unroll
        for (int r = 0; r < 4; r++) {
            const int g = m0 + rl + r;
            if (g < count) {
                u16* orow = hg + (size_t)(rbase + g) * FF_DIM + n0;
                #pragma unroll
                for (int nf = 0; nf < 2; nf++) {
                    const int col = wn * 32 + nf * 16 + fr;
                    float hv = acc_h[mf][nf][r] + b1p[col];
                    float gv = acc_g[mf][nf][r] + bgp[col];
                    float sig = 1.f / (1.f + expf(-gv));
                    orow[col] = f2bf(gv * sig * hv);
                }
            }
        }
    }
}

// ---------------- pass 2: contrib[slot] = w * (hg @ W2 + b2) ----------------
// R11/R17 config: BM=128 BN=128 BK=64, 4 waves (2Mx2N, 64x64/wave),
// 2x32KB dbuf -> 2 blocks/CU, depth-1 counted vmcnt(8), sigma(r)=r&7 swizzle,
// both operands bf16 via global_load_lds (w2t prepass).

__global__ __launch_bounds__(256, 2) void k_pass2(
    const u16* __restrict__ hg,
    const u16* __restrict__ w2t, const float* __restrict__ b2v,
    const int* __restrict__ cnt, const int* __restrict__ basep,
    const int* __restrict__ row_token, const int* __restrict__ row_slot,
    const float* __restrict__ row_weight,
    const int* __restrict__ ntp, const int* __restrict__ te, const int* __restrict__ tm,
    float* __restrict__ contrib)
{
    const int ty = blockIdx.y;
    if (ty >= *ntp) return;
    const int e = te[ty];
    const int m0 = tm[ty];
    const int count = cnt[e];
    const int rbase = basep[e];
    const int n0 = blockIdx.x * 128;

    __shared__ __align__(16) u16 LDS[2 * 16384];

    const int tid = threadIdx.x;
    const int l = tid & 63;
    const int w = tid >> 6;

    const int rb = tid >> 3;                        // 0..31
    const int sw0 = ((tid & 7) ^ ((tid >> 3) & 7)) * 8;
    const u16* sA[4];
    #pragma unroll
    for (int s = 0; s < 4; s++) {
        int g = m0 + rb + s * 32; if (g > count - 1) g = count - 1;
        sA[s] = hg + (size_t)(rbase + g) * FF_DIM + sw0;
    }
    const u16* sB[4];
    #pragma unroll
    for (int s = 0; s < 4; s++)
        sB[s] = w2t + ((size_t)e * D_DIM + (size_t)(n0 + rb + s * 32)) * FF_DIM + sw0;

    const int wm = w >> 1, wn = w & 1;   // 2M x 2N
    const int fr = l & 15, q = l >> 4;
    const int s7 = fr & 7;

    f32x4 acc[4][4];
    const f32x4 z4 = {0.f, 0.f, 0.f, 0.f};
    #pragma unroll
    for (int mf = 0; mf < 4; mf++)
        #pragma unroll
        for (int nf = 0; nf < 4; nf++) acc[mf][nf] = z4;

    auto STAGE = [&](int b, int k0) {
        #pragma unroll
        for (int s = 0; s < 4; s++)
            GLOAD16(sA[s] + k0, &LDS[b * 16384 + s * 2048 + tid * 8]);
        #pragma unroll
        for (int s = 0; s < 4; s++)
            GLOAD16(sB[s] + k0, &LDS[b * 16384 + 8192 + s * 2048 + tid * 8]);
    };

    const int NT = FF_DIM / 64;   // 64
    STAGE(0, 0);
    int cur = 0;
    #pragma unroll 1
    for (int t = 0; t < NT; ++t) {
        if (t + 1 < NT) {
            STAGE(cur ^ 1, (t + 1) * 64);
            asm volatile("s_waitcnt vmcnt(8)" ::: "memory");
        } else {
            asm volatile("s_waitcnt vmcnt(0)" ::: "memory");
        }
        __builtin_amdgcn_s_barrier();
        CFENCE();
        const int ab = cur * 16384;
        #pragma unroll
        for (int kk = 0; kk < 2; kk++) {
            const int rs = ((kk * 4 + q) ^ s7) * 8;
            bf16x8 a[4], bb[4];
            #pragma unroll
            for (int mf = 0; mf < 4; mf++)
                a[mf] = *(const bf16x8*)&LDS[ab + (wm * 64 + mf * 16 + fr) * 64 + rs];
            #pragma unroll
            for (int nf = 0; nf < 4; nf++)
                bb[nf] = *(const bf16x8*)&LDS[ab + 8192 + (wn * 64 + nf * 16 + fr) * 64 + rs];
            __builtin_amdgcn_s_setprio(1);
            #pragma unroll
            for (int mf = 0; mf < 4; mf++)
                #pragma unroll
                for (int nf = 0; nf < 4; nf++)
                    acc[mf][nf] = MFMA(a[mf], bb[nf], acc[mf][nf]);
            __builtin_amdgcn_s_setprio(0);
        }
        CFENCE();
        __builtin_amdgcn_s_barrier();
        cur ^= 1;
    }

    const float* b2p = b2v + (size_t)e * D_DIM + n0;
    #pragma unroll
    for (int mf = 0; mf < 4; mf++) {
        const int rl = wm * 64 + mf * 16 + q * 4;
        #pragma unroll
        for (int r = 0; r < 4; r++) {
            const int g = m0 + rl + r;
            if (g < count) {
                const int token = row_token[rbase + g];
                const int slot  = row_slot[rbase + g];
                const float wgt_ = row_weight[rbase + g];
                float* orow = contrib + ((size_t)slot * T_TOK + token) * D_DIM + n0;
                #pragma unroll
                for (int nf = 0; nf < 4; nf++) {
                    const int col = wn * 64 + nf * 16 + fr;
                    orow[col] = wgt_ * (acc[mf][nf][r] + b2p[col]);
                }
            }
        }
    }
}

__global__ void k_combine(const float* __restrict__ contrib, float* __restrict__ out) {
    int i = blockIdx.x * blockDim.x + threadIdx.x;
    const f32x4* c0 = (const f32x4*)contrib;
    const f32x4* c1 = c0 + ((size_t)T_TOK * D_DIM / 4);
    f32x4* o = (f32x4*)out;
    o[i] = c0[i] + c1[i];
}

// ---------------- launch ----------------

extern "C" void kernel_launch(void* const* d_in, const int* in_sizes, int n_in,
                              void* d_out, int out_size, void* d_ws, size_t ws_size,
                              hipStream_t stream)
{
    (void)in_sizes; (void)n_in; (void)out_size; (void)ws_size;
    const float* x  = (const float*)d_in[0];
    const float* Wr = (const float*)d_in[1];
    const float* W1 = (const float*)d_in[2];
    const float* b1 = (const float*)d_in[3];
    const float* Wg = (const float*)d_in[4];
    const float* bg = (const float*)d_in[5];
    const float* W2 = (const float*)d_in[6];
    const float* b2 = (const float*)d_in[7];
    float* out = (float*)d_out;

    char* ws = (char*)d_ws;
    u16* xbf = (u16*)ws;             ws += (size_t)T_TOK * D_DIM * sizeof(u16);
    u16* w2t = (u16*)ws;             ws += (size_t)E_EXP * D_DIM * FF_DIM * sizeof(u16);
    u16* hg = (u16*)ws;              ws += (size_t)NROWS * FF_DIM * sizeof(u16);
    float* contrib = (float*)ws;     ws += (size_t)2 * T_TOK * D_DIM * sizeof(float);
    int* tok_e = (int*)ws;           ws += (size_t)T_TOK * 2 * sizeof(int);
    float* tok_w = (float*)ws;       ws += (size_t)T_TOK * 2 * sizeof(float);
    int* row_token = (int*)ws;       ws += (size_t)NROWS * sizeof(int);
    int* row_slot = (int*)ws;        ws += (size_t)NROWS * sizeof(int);
    float* row_weight = (float*)ws;  ws += (size_t)NROWS * sizeof(float);
    int* cnt = (int*)ws;             ws += 8 * sizeof(int);
    int* basep = (int*)ws;           ws += 8 * sizeof(int);
    int* cursor = (int*)ws;          ws += 8 * sizeof(int);
    float* probsum = (float*)ws;     ws += 8 * sizeof(float);
    int* nt1 = (int*)ws;             ws += sizeof(int);
    int* nt2 = (int*)ws;             ws += sizeof(int);
    int* te1 = (int*)ws;             ws += MAXT1 * sizeof(int);
    int* tm1 = (int*)ws;             ws += MAXT1 * sizeof(int);
    int* te2 = (int*)ws;             ws += MAXT2 * sizeof(int);
    int* tm2 = (int*)ws;             ws += MAXT2 * sizeof(int);

    k_cvt_w2<<<dim3(D_DIM / 64, FF_DIM / 64, E_EXP), 256, 0, stream>>>(W2, w2t, cnt, probsum);
    k_router<<<T_TOK / 4, 256, 0, stream>>>(x, Wr, xbf, tok_e, tok_w, cnt, probsum);
    k_prefix<<<1, 64, 0, stream>>>(cnt, probsum, basep, cursor, out + (size_t)T_TOK * D_DIM,
                                   nt1, te1, tm1, nt2, te2, tm2);
    k_assign<<<T_TOK / 256, 256, 0, stream>>>(tok_e, tok_w, basep, cursor, row_token, row_slot, row_weight);
    k_pass1<<<dim3(FF_DIM / 128, MAXT1), 512, 0, stream>>>(xbf, W1, Wg, b1, bg, cnt, basep, row_token,
                                                           nt1, te1, tm1, hg);
    k_pass2<<<dim3(D_DIM / 128, MAXT2), 256, 0, stream>>>(hg, w2t, b2, cnt, basep, row_token, row_slot, row_weight,
                                                          nt2, te2, tm2, contrib);
    k_combine<<<(T_TOK * D_DIM / 4) / 256, 256, 0, stream>>>(contrib, out);
}

// Round 23
// 411.524 us; speedup vs baseline: 1.1456x; 1.1179x over previous
//
#include <hip/hip_runtime.h>
#include <hip/hip_bf16.h>
#include <math.h>

#define T_TOK 4096
#define D_DIM 1024
#define E_EXP 8
#define FF_DIM 4096
#define NROWS (T_TOK * 2)
#define MAXT1 40   // max m-tiles (BM=256): 8192/256 + 8
#define MAXT2 72   // max m-tiles (BM=128): 8192/128 + 8
#define NRBLK 1024          // router blocks (4 tokens each)
#define NW2TILE 8192        // W2 64x64 tiles: 8 experts * 64 FF-tiles * 16 D-tiles

typedef unsigned short u16;
typedef unsigned int u32;
typedef __attribute__((ext_vector_type(8))) short bf16x8;
typedef __attribute__((ext_vector_type(4))) float f32x4;
typedef __attribute__((ext_vector_type(2))) unsigned int u32x2;
typedef __attribute__((ext_vector_type(4))) short s16x4;

__device__ __forceinline__ u16 f2bf(float f) {
    union { float f; unsigned u; } v; v.f = f;
    unsigned r = v.u + 0x7FFFu + ((v.u >> 16) & 1u);
    return (u16)(r >> 16);
}

typedef const __attribute__((address_space(1))) u32* gas1_t;
typedef __attribute__((address_space(3))) u32* las3_t;
#define GLOAD16(g, l) __builtin_amdgcn_global_load_lds((gas1_t)(const void*)(g), (las3_t)(void*)(l), 16, 0, 0)
#define MFMA(a, b, c) __builtin_amdgcn_mfma_f32_16x16x32_bf16((a), (b), (c), 0, 0, 0)
#define CVTPK(dst, lo, hi) asm("v_cvt_pk_bf16_f32 %0, %1, %2" : "=v"(dst) : "v"(lo), "v"(hi))
#define CFENCE() asm volatile("" ::: "memory")
// B-tile swizzle for fused pass1: sigma(row) = (row ^ (row>>2)) & 7.
#define SIGB(r) (((r) ^ ((r) >> 2)) & 7)

// ---------------- merged front-end: router + x->bf16 + W2 transpose ----------------
// Blocks [0, NRBLK): router for 4 tokens each; ALSO converts x->xbf in the same
// pass. Per-block counts/probsums go to blk_cnt/blk_ps (no global atomics, no
// init dependency). Blocks [NRBLK, NRBLK+NW2TILE): one 64x64 W2 transpose tile
// each (fp32 [E][FF][D] -> bf16 [E][D][FF]). Independent work, concurrent BW use.
__global__ __launch_bounds__(256) void k_front(
    const float* __restrict__ x, const float* __restrict__ Wr,
    u16* __restrict__ xbf,
    int* __restrict__ tok_e, float* __restrict__ tok_w,
    int* __restrict__ blk_cnt, float* __restrict__ blk_ps,
    const float* __restrict__ W2, u16* __restrict__ w2t)
{
    const int tid = threadIdx.x;
    const int bid = blockIdx.x;

    if (bid < NRBLK) {
        __shared__ float bp[E_EXP];
        __shared__ int   bc[E_EXP];
        if (tid < E_EXP) { bp[tid] = 0.f; bc[tid] = 0; }
        __syncthreads();
        const int wave = tid >> 6, lane = tid & 63;
        const int t = bid * 4 + wave;
        const float* xt = x + (size_t)t * D_DIM;
        u16* xo = xbf + (size_t)t * D_DIM;
        float a[E_EXP] = {0.f,0.f,0.f,0.f,0.f,0.f,0.f,0.f};
        for (int j = lane; j < D_DIM; j += 64) {
            float xv = xt[j];
            xo[j] = f2bf(xv);
            #pragma unroll
            for (int e = 0; e < E_EXP; e++) a[e] = fmaf(xv, Wr[e * D_DIM + j], a[e]);
        }
        #pragma unroll
        for (int e = 0; e < E_EXP; e++) {
            #pragma unroll
            for (int off = 32; off; off >>= 1) a[e] += __shfl_xor(a[e], off, 64);
        }
        if (lane == 0) {
            float mx = a[0];
            #pragma unroll
            for (int e = 1; e < E_EXP; e++) mx = fmaxf(mx, a[e]);
            float p[E_EXP], s = 0.f;
            #pragma unroll
            for (int e = 0; e < E_EXP; e++) { p[e] = expf(a[e] - mx); s += p[e]; }
            float inv = 1.f / s;
            #pragma unroll
            for (int e = 0; e < E_EXP; e++) { p[e] *= inv; atomicAdd(&bp[e], p[e]); }
            int e0 = 0; float v0 = p[0];
            #pragma unroll
            for (int e = 1; e < E_EXP; e++) if (p[e] > v0) { v0 = p[e]; e0 = e; }
            int e1 = -1; float v1 = -1.f;
            #pragma unroll
            for (int e = 0; e < E_EXP; e++) if (e != e0 && p[e] > v1) { v1 = p[e]; e1 = e; }
            float sv = v0 + v1 + 1e-6f;
            tok_e[2*t] = e0; tok_e[2*t+1] = e1;
            tok_w[2*t] = v0 / sv; tok_w[2*t+1] = v1 / sv;
            atomicAdd(&bc[e0], 1); atomicAdd(&bc[e1], 1);
        }
        __syncthreads();
        if (tid < E_EXP) {
            blk_cnt[bid * E_EXP + tid] = bc[tid];
            blk_ps[bid * E_EXP + tid]  = bp[tid];
        }
    } else {
        __shared__ u16 tbuf[64][68];
        const int tile = bid - NRBLK;                 // 0..8191
        const int e2 = tile >> 10;                    // expert
        const int rem = tile & 1023;
        const int r0 = (rem >> 4) * 64;               // FF offset
        const int c0 = (rem & 15) * 64;               // D offset
        const float* in = W2 + ((size_t)e2 * FF_DIM + r0) * D_DIM + c0;
        u16* out = w2t + ((size_t)e2 * D_DIM + c0) * FF_DIM + r0;
        const int lr = tid >> 4, lc = (tid & 15) * 4;
        #pragma unroll
        for (int i = 0; i < 4; i++) {
            const int r = lr + i * 16;
            f32x4 v = *(const f32x4*)(in + (size_t)r * D_DIM + lc);
            s16x4 w;
            #pragma unroll
            for (int j = 0; j < 4; j++) w[j] = (short)f2bf(v[j]);
            *(s16x4*)&tbuf[r][lc] = w;
        }
        __syncthreads();
        #pragma unroll
        for (int i = 0; i < 4; i++) {
            const int c = lr + i * 16;
            s16x4 w;
            #pragma unroll
            for (int j = 0; j < 4; j++) w[j] = (short)tbuf[lc + j][c];
            *(s16x4*)(out + (size_t)c * FF_DIM + lc) = w;
        }
    }
}

// ---------------- merged prefix + assign (single block) ----------------
// Reduces blk_cnt/blk_ps -> cnt/probsum, computes prefixes, lb, tile tables,
// then assigns all token-slots with LDS cursors (bitwise-deterministic output).
__global__ __launch_bounds__(256) void k_prefix_assign(
    const int* __restrict__ blk_cnt, const float* __restrict__ blk_ps,
    const int* __restrict__ tok_e, const float* __restrict__ tok_w,
    int* __restrict__ cnt, int* __restrict__ basep,
    float* __restrict__ out_lb,
    int* __restrict__ nt1, int* __restrict__ te1, int* __restrict__ tm1,
    int* __restrict__ nt2, int* __restrict__ te2, int* __restrict__ tm2,
    int* __restrict__ row_token, int* __restrict__ row_slot,
    float* __restrict__ row_weight)
{
    __shared__ int   s_cnt[E_EXP];
    __shared__ int   s_base[E_EXP];
    __shared__ int   s_cur[E_EXP];
    const int tid = threadIdx.x;

    // reduce: e = tid>>5 (8 groups of 32 lanes); each lane sums blocks lane,lane+32,...
    const int e = tid >> 5, lane32 = tid & 31;
    int ce = 0; float pe = 0.f;
    for (int b = lane32; b < NRBLK; b += 32) {
        ce += blk_cnt[b * E_EXP + e];
        pe += blk_ps[b * E_EXP + e];
    }
    #pragma unroll
    for (int off = 16; off; off >>= 1) {
        ce += __shfl_xor(ce, off, 32);
        pe += __shfl_xor(pe, off, 32);
    }
    __shared__ float s_ps[E_EXP];
    if (lane32 == 0) { s_cnt[e] = ce; s_ps[e] = pe; }
    if (tid < E_EXP) s_cur[tid] = 0;
    __syncthreads();

    if (tid == 0) {
        int b = 0; float lb = 0.f;
        for (int k = 0; k < E_EXP; k++) {
            s_base[k] = b;
            basep[k] = b;
            cnt[k] = s_cnt[k];
            lb += ((float)s_cnt[k] / (8192.f + 1e-6f)) * s_ps[k];
            b += s_cnt[k];
        }
        *out_lb = lb * (float)E_EXP;
        int n1 = 0, n2 = 0;
        for (int k = 0; k < E_EXP; k++) {
            for (int m = 0; m < s_cnt[k]; m += 256) { te1[n1] = k; tm1[n1] = m; n1++; }
            for (int m = 0; m < s_cnt[k]; m += 128) { te2[n2] = k; tm2[n2] = m; n2++; }
        }
        *nt1 = n1; *nt2 = n2;
    }
    __syncthreads();

    for (int t = tid; t < T_TOK; t += 256) {
        #pragma unroll
        for (int k = 0; k < 2; k++) {
            int ex = tok_e[2*t + k];
            int pos = s_base[ex] + atomicAdd(&s_cur[ex], 1);
            row_token[pos] = t; row_slot[pos] = k; row_weight[pos] = tok_w[2*t + k];
        }
    }
}

// ---------------- pass 1: hg = silu(x@Wg) * (x@W1) ----------------
// R17/R19/R21 fused version: BM=256 BN=128 BK=64, 8 waves; W1/Wg consumed fp32
// from [E][D][FF] with in-kernel transpose-convert (cvt_pk + b64 writes, SIGB
// swizzle); A (xbf bf16) via global_load_lds. One drain+barrier per K-tile.

__global__ __launch_bounds__(512, 2) void k_pass1(
    const u16* __restrict__ xbf,
    const float* __restrict__ W1, const float* __restrict__ Wg,
    const float* __restrict__ b1v, const float* __restrict__ bgv,
    const int* __restrict__ cnt, const int* __restrict__ basep,
    const int* __restrict__ row_token,
    const int* __restrict__ ntp, const int* __restrict__ te, const int* __restrict__ tm,
    u16* __restrict__ hg)
{
    const int ty = blockIdx.y;
    if (ty >= *ntp) return;
    const int e = te[ty];
    const int m0 = tm[ty];
    const int count = cnt[e];
    const int rbase = basep[e];
    const int n0 = blockIdx.x * 128;

    __shared__ __align__(16) u16 LDS[2 * 32768];

    const int tid = threadIdx.x;
    const int l = tid & 63;
    const int w = tid >> 6;

    const int rb = tid >> 3;
    const int swA = ((tid & 7) ^ ((tid >> 3) & 7)) * 8;
    const u16* sA[4];
    #pragma unroll
    for (int s = 0; s < 4; s++) {
        int g = m0 + rb + s * 64; if (g > count - 1) g = count - 1;
        sA[s] = xbf + (size_t)row_token[rbase + g] * D_DIM + swA;
    }

    const int nq = tid & 31;
    const int kq = tid >> 5;
    const float* pBh = W1 + ((size_t)e * D_DIM + kq * 4) * FF_DIM + n0 + nq * 4;
    const float* pBg = Wg + ((size_t)e * D_DIM + kq * 4) * FF_DIM + n0 + nq * 4;
    const int cW = kq >> 1;
    const int offW = (kq & 1) * 4;
    int wdst[4];
    #pragma unroll
    for (int j = 0; j < 4; j++) {
        const int row = nq * 4 + j;
        wdst[j] = row * 64 + (cW ^ SIGB(row)) * 8 + offW;
    }

    const int wm = w >> 2, wn = w & 3;
    const int fr = l & 15, q = l >> 4;
    const int s7 = fr & 7;

    f32x4 acc_h[8][2], acc_g[8][2];
    const f32x4 z4 = {0.f, 0.f, 0.f, 0.f};
    #pragma unroll
    for (int mf = 0; mf < 8; mf++)
        #pragma unroll
        for (int nf = 0; nf < 2; nf++) { acc_h[mf][nf] = z4; acc_g[mf][nf] = z4; }

    f32x4 vb0, vb1, vb2, vb3;

    #define LOADB1(P, K0) do { \
        const float* p_ = (P) + (size_t)(K0) * FF_DIM; \
        vb0 = *(const f32x4*)(p_); \
        vb1 = *(const f32x4*)(p_ + FF_DIM); \
        vb2 = *(const f32x4*)(p_ + 2 * FF_DIM); \
        vb3 = *(const f32x4*)(p_ + 3 * FF_DIM); \
    } while (0)

    #define CVTW1(BASE) do { \
        _Pragma("unroll") \
        for (int j = 0; j < 4; j++) { \
            u32 lo_, hi_; u32x2 wv_; \
            CVTPK(lo_, vb0[j], vb1[j]); \
            CVTPK(hi_, vb2[j], vb3[j]); \
            wv_.x = lo_; wv_.y = hi_; \
            *(u32x2*)&LDS[(BASE) + wdst[j]] = wv_; \
        } \
    } while (0)

    #define STAGE_A1(B, K0) do { \
        _Pragma("unroll") \
        for (int s = 0; s < 4; s++) \
            GLOAD16(sA[s] + (K0), &LDS[(B) * 32768 + s * 4096 + tid * 8]); \
    } while (0)

    auto COMP = [&](int kk, int ab) {
        const int rsA = ((kk * 4 + q) ^ s7) * 8;
        const int rB0 = wn * 32 + fr, rB1 = wn * 32 + 16 + fr;
        const int cb0 = ((kk * 4 + q) ^ SIGB(rB0)) * 8;
        const int cb1 = ((kk * 4 + q) ^ SIGB(rB1)) * 8;
        bf16x8 bh0 = *(const bf16x8*)&LDS[ab + 16384 + rB0 * 64 + cb0];
        bf16x8 bg0 = *(const bf16x8*)&LDS[ab + 24576 + rB0 * 64 + cb0];
        bf16x8 bh1 = *(const bf16x8*)&LDS[ab + 16384 + rB1 * 64 + cb1];
        bf16x8 bg1 = *(const bf16x8*)&LDS[ab + 24576 + rB1 * 64 + cb1];
        #define LDA1(i) (*(const bf16x8*)&LDS[ab + (wm * 128 + (i) * 16 + fr) * 64 + rsA])
        #define MF4(areg, i) do { \
            __builtin_amdgcn_s_setprio(1); \
            acc_h[i][0] = MFMA(areg, bh0, acc_h[i][0]); \
            acc_h[i][1] = MFMA(areg, bh1, acc_h[i][1]); \
            acc_g[i][0] = MFMA(areg, bg0, acc_g[i][0]); \
            acc_g[i][1] = MFMA(areg, bg1, acc_g[i][1]); \
            __builtin_amdgcn_s_setprio(0); } while (0)
        bf16x8 aA = LDA1(0);
        bf16x8 aB = LDA1(1);
        bf16x8 aC;
        aC = LDA1(2); MF4(aA, 0);
        aA = LDA1(3); MF4(aB, 1);
        aB = LDA1(4); MF4(aC, 2);
        aC = LDA1(5); MF4(aA, 3);
        aA = LDA1(6); MF4(aB, 4);
        aB = LDA1(7); MF4(aC, 5);
        MF4(aA, 6);
        MF4(aB, 7);
        #undef LDA1
        #undef MF4
    };

    const int NT = D_DIM / 64;   // 16
    LOADB1(pBh, 0);
    CVTW1(0 + 16384);
    STAGE_A1(0, 0);
    LOADB1(pBg, 0);
    CVTW1(0 + 24576);
    asm volatile("s_waitcnt vmcnt(0) lgkmcnt(0)" ::: "memory");
    __builtin_amdgcn_s_barrier();
    CFENCE();

    int b = 0;
    #pragma unroll 1
    for (int t = 0; t < NT; ++t) {
        const int ab = b * 32768;
        const int nboff = (b ^ 1) * 32768;
        const int kN = (t + 1 < NT ? t + 1 : NT - 1) * 64;
        LOADB1(pBh, kN);
        COMP(0, ab);
        CVTW1(nboff + 16384);
        STAGE_A1(b ^ 1, kN);
        LOADB1(pBg, kN);
        COMP(1, ab);
        CVTW1(nboff + 24576);
        asm volatile("s_waitcnt vmcnt(0) lgkmcnt(0)" ::: "memory");
        __builtin_amdgcn_s_barrier();
        CFENCE();
        b ^= 1;
    }
    asm volatile("s_waitcnt vmcnt(0)" ::: "memory");
    #undef LOADB1
    #undef CVTW1
    #undef STAGE_A1

    const float* b1p = b1v + (size_t)e * FF_DIM + n0;
    const float* bgp = bgv + (size_t)e * FF_DIM + n0;
    #pragma unroll
    for (int mf = 0; mf < 8; mf++) {
        const int rl = wm * 128 + mf * 16 + q * 4;
        #pragma unroll
        for (int r = 0; r < 4; r++) {
            const int g = m0 + rl + r;
            if (g < count) {
                u16* orow = hg + (size_t)(rbase + g) * FF_DIM + n0;
                #pragma unroll
                for (int nf = 0; nf < 2; nf++) {
                    const int col = wn * 32 + nf * 16 + fr;
                    float hv = acc_h[mf][nf][r] + b1p[col];
                    float gv = acc_g[mf][nf][r] + bgp[col];
                    float sig = 1.f / (1.f + expf(-gv));
                    orow[col] = f2bf(gv * sig * hv);
                }
            }
        }
    }
}

// ---------------- pass 2: contrib[slot] = w * (hg @ W2 + b2) ----------------
// R11/R17 config: BM=128 BN=128 BK=64, 4 waves (2Mx2N, 64x64/wave),
// 2x32KB dbuf -> 2 blocks/CU, depth-1 counted vmcnt(8), sigma(r)=r&7 swizzle,
// both operands bf16 via global_load_lds (w2t from k_front).

__global__ __launch_bounds__(256, 2) void k_pass2(
    const u16* __restrict__ hg,
    const u16* __restrict__ w2t, const float* __restrict__ b2v,
    const int* __restrict__ cnt, const int* __restrict__ basep,
    const int* __restrict__ row_token, const int* __restrict__ row_slot,
    const float* __restrict__ row_weight,
    const int* __restrict__ ntp, const int* __restrict__ te, const int* __restrict__ tm,
    float* __restrict__ contrib)
{
    const int ty = blockIdx.y;
    if (ty >= *ntp) return;
    const int e = te[ty];
    const int m0 = tm[ty];
    const int count = cnt[e];
    const int rbase = basep[e];
    const int n0 = blockIdx.x * 128;

    __shared__ __align__(16) u16 LDS[2 * 16384];

    const int tid = threadIdx.x;
    const int l = tid & 63;
    const int w = tid >> 6;

    const int rb = tid >> 3;                        // 0..31
    const int sw0 = ((tid & 7) ^ ((tid >> 3) & 7)) * 8;
    const u16* sA[4];
    #pragma unroll
    for (int s = 0; s < 4; s++) {
        int g = m0 + rb + s * 32; if (g > count - 1) g = count - 1;
        sA[s] = hg + (size_t)(rbase + g) * FF_DIM + sw0;
    }
    const u16* sB[4];
    #pragma unroll
    for (int s = 0; s < 4; s++)
        sB[s] = w2t + ((size_t)e * D_DIM + (size_t)(n0 + rb + s * 32)) * FF_DIM + sw0;

    const int wm = w >> 1, wn = w & 1;   // 2M x 2N
    const int fr = l & 15, q = l >> 4;
    const int s7 = fr & 7;

    f32x4 acc[4][4];
    const f32x4 z4 = {0.f, 0.f, 0.f, 0.f};
    #pragma unroll
    for (int mf = 0; mf < 4; mf++)
        #pragma unroll
        for (int nf = 0; nf < 4; nf++) acc[mf][nf] = z4;

    auto STAGE = [&](int b, int k0) {
        #pragma unroll
        for (int s = 0; s < 4; s++)
            GLOAD16(sA[s] + k0, &LDS[b * 16384 + s * 2048 + tid * 8]);
        #pragma unroll
        for (int s = 0; s < 4; s++)
            GLOAD16(sB[s] + k0, &LDS[b * 16384 + 8192 + s * 2048 + tid * 8]);
    };

    const int NT = FF_DIM / 64;   // 64
    STAGE(0, 0);
    int cur = 0;
    #pragma unroll 1
    for (int t = 0; t < NT; ++t) {
        if (t + 1 < NT) {
            STAGE(cur ^ 1, (t + 1) * 64);
            asm volatile("s_waitcnt vmcnt(8)" ::: "memory");
        } else {
            asm volatile("s_waitcnt vmcnt(0)" ::: "memory");
        }
        __builtin_amdgcn_s_barrier();
        CFENCE();
        const int ab = cur * 16384;
        #pragma unroll
        for (int kk = 0; kk < 2; kk++) {
            const int rs = ((kk * 4 + q) ^ s7) * 8;
            bf16x8 a[4], bb[4];
            #pragma unroll
            for (int mf = 0; mf < 4; mf++)
                a[mf] = *(const bf16x8*)&LDS[ab + (wm * 64 + mf * 16 + fr) * 64 + rs];
            #pragma unroll
            for (int nf = 0; nf < 4; nf++)
                bb[nf] = *(const bf16x8*)&LDS[ab + 8192 + (wn * 64 + nf * 16 + fr) * 64 + rs];
            __builtin_amdgcn_s_setprio(1);
            #pragma unroll
            for (int mf = 0; mf < 4; mf++)
                #pragma unroll
                for (int nf = 0; nf < 4; nf++)
                    acc[mf][nf] = MFMA(a[mf], bb[nf], acc[mf][nf]);
            __builtin_amdgcn_s_setprio(0);
        }
        CFENCE();
        __builtin_amdgcn_s_barrier();
        cur ^= 1;
    }

    const float* b2p = b2v + (size_t)e * D_DIM + n0;
    #pragma unroll
    for (int mf = 0; mf < 4; mf++) {
        const int rl = wm * 64 + mf * 16 + q * 4;
        #pragma unroll
        for (int r = 0; r < 4; r++) {
            const int g = m0 + rl + r;
            if (g < count) {
                const int token = row_token[rbase + g];
                const int slot  = row_slot[rbase + g];
                const float wgt_ = row_weight[rbase + g];
                float* orow = contrib + ((size_t)slot * T_TOK + token) * D_DIM + n0;
                #pragma unroll
                for (int nf = 0; nf < 4; nf++) {
                    const int col = wn * 64 + nf * 16 + fr;
                    orow[col] = wgt_ * (acc[mf][nf][r] + b2p[col]);
                }
            }
        }
    }
}

__global__ void k_combine(const float* __restrict__ contrib, float* __restrict__ out) {
    int i = blockIdx.x * blockDim.x + threadIdx.x;
    const f32x4* c0 = (const f32x4*)contrib;
    const f32x4* c1 = c0 + ((size_t)T_TOK * D_DIM / 4);
    f32x4* o = (f32x4*)out;
    o[i] = c0[i] + c1[i];
}

// ---------------- launch ----------------

extern "C" void kernel_launch(void* const* d_in, const int* in_sizes, int n_in,
                              void* d_out, int out_size, void* d_ws, size_t ws_size,
                              hipStream_t stream)
{
    (void)in_sizes; (void)n_in; (void)out_size; (void)ws_size;
    const float* x  = (const float*)d_in[0];
    const float* Wr = (const float*)d_in[1];
    const float* W1 = (const float*)d_in[2];
    const float* b1 = (const float*)d_in[3];
    const float* Wg = (const float*)d_in[4];
    const float* bg = (const float*)d_in[5];
    const float* W2 = (const float*)d_in[6];
    const float* b2 = (const float*)d_in[7];
    float* out = (float*)d_out;

    char* ws = (char*)d_ws;
    u16* xbf = (u16*)ws;             ws += (size_t)T_TOK * D_DIM * sizeof(u16);
    u16* w2t = (u16*)ws;             ws += (size_t)E_EXP * D_DIM * FF_DIM * sizeof(u16);
    u16* hg = (u16*)ws;              ws += (size_t)NROWS * FF_DIM * sizeof(u16);
    float* contrib = (float*)ws;     ws += (size_t)2 * T_TOK * D_DIM * sizeof(float);
    int* tok_e = (int*)ws;           ws += (size_t)T_TOK * 2 * sizeof(int);
    float* tok_w = (float*)ws;       ws += (size_t)T_TOK * 2 * sizeof(float);
    int* row_token = (int*)ws;       ws += (size_t)NROWS * sizeof(int);
    int* row_slot = (int*)ws;        ws += (size_t)NROWS * sizeof(int);
    float* row_weight = (float*)ws;  ws += (size_t)NROWS * sizeof(float);
    int* blk_cnt = (int*)ws;         ws += (size_t)NRBLK * E_EXP * sizeof(int);
    float* blk_ps = (float*)ws;      ws += (size_t)NRBLK * E_EXP * sizeof(float);
    int* cnt = (int*)ws;             ws += 8 * sizeof(int);
    int* basep = (int*)ws;           ws += 8 * sizeof(int);
    int* nt1 = (int*)ws;             ws += sizeof(int);
    int* nt2 = (int*)ws;             ws += sizeof(int);
    int* te1 = (int*)ws;             ws += MAXT1 * sizeof(int);
    int* tm1 = (int*)ws;             ws += MAXT1 * sizeof(int);
    int* te2 = (int*)ws;             ws += MAXT2 * sizeof(int);
    int* tm2 = (int*)ws;             ws += MAXT2 * sizeof(int);

    k_front<<<NRBLK + NW2TILE, 256, 0, stream>>>(x, Wr, xbf, tok_e, tok_w,
                                                 blk_cnt, blk_ps, W2, w2t);
    k_prefix_assign<<<1, 256, 0, stream>>>(blk_cnt, blk_ps, tok_e, tok_w,
                                           cnt, basep, out + (size_t)T_TOK * D_DIM,
                                           nt1, te1, tm1, nt2, te2, tm2,
                                           row_token, row_slot, row_weight);
    k_pass1<<<dim3(FF_DIM / 128, MAXT1), 512, 0, stream>>>(xbf, W1, Wg, b1, bg, cnt, basep, row_token,
                                                           nt1, te1, tm1, hg);
    k_pass2<<<dim3(D_DIM / 128, MAXT2), 256, 0, stream>>>(hg, w2t, b2, cnt, basep, row_token, row_slot, row_weight,
                                                          nt2, te2, tm2, contrib);
    k_combine<<<(T_TOK * D_DIM / 4) / 256, 256, 0, stream>>>(contrib, out);
}